// Round 1
// baseline (672.783 us; speedup 1.0000x reference)
//
#include <hip/hip_runtime.h>
#include <cstddef>

#define B_    8
#define C_    512
#define HW_   1024
#define NHEAD 8
#define DH    64
#define GRP   32
#define CPG   16
#define O3    1536
#define COND  512
#define EPSV  1e-5f

// workspace layout (float offsets)
#define OFF_STATS 0                               // B_*GRP*2 = 512
#define OFF_A     512                             // B_*C_ = 4096
#define OFF_B     (OFF_A + B_*C_)                 // 4608
#define OFF_QKV   (OFF_B + B_*C_)                 // 8704, size B_*O3*HW_ = 12582912
#define OFF_Y     (OFF_QKV + (size_t)B_*O3*HW_)   // size B_*C_*HW_ = 4194304

// ---------------- 1. GroupNorm statistics ----------------
__global__ __launch_bounds__(256) void stats_kernel(const float* __restrict__ x,
                                                    float* __restrict__ ws) {
    int bid = blockIdx.x;            // n*GRP + g
    int n = bid >> 5, g = bid & 31;
    const float* base = x + ((size_t)n * C_ + g * CPG) * HW_;
    float s1 = 0.f, s2 = 0.f;
    for (int i = threadIdx.x; i < CPG * HW_; i += 256) {
        float v = base[i];
        s1 += v; s2 += v * v;
    }
    __shared__ float r1[256], r2[256];
    r1[threadIdx.x] = s1; r2[threadIdx.x] = s2;
    __syncthreads();
    for (int s = 128; s > 0; s >>= 1) {
        if (threadIdx.x < s) {
            r1[threadIdx.x] += r1[threadIdx.x + s];
            r2[threadIdx.x] += r2[threadIdx.x + s];
        }
        __syncthreads();
    }
    if (threadIdx.x == 0) {
        const float inv = 1.f / (CPG * HW_);
        float mean = r1[0] * inv;
        float var  = r2[0] * inv - mean * mean;
        float rstd = rsqrtf(var + EPSV);
        ws[OFF_STATS + bid * 2]     = mean;
        ws[OFF_STATS + bid * 2 + 1] = rstd;
    }
}

// ---------------- 2. cond @ W_map^T + b_map, fold into per-(n,c) affine ----------------
__global__ __launch_bounds__(256) void map_kernel(const float* __restrict__ cond,
                                                  const float* __restrict__ Wmap,
                                                  const float* __restrict__ bmap,
                                                  float* __restrict__ ws) {
    int n = blockIdx.x;
    __shared__ float cs[COND];
    __shared__ float ss[2 * C_];
    int t = threadIdx.x;
    cs[t]       = cond[n * COND + t];
    cs[t + 256] = cond[n * COND + t + 256];
    __syncthreads();
    for (int o = t; o < 2 * C_; o += 256) {
        const float* wrow = Wmap + (size_t)o * COND;
        float acc = 0.f;
        for (int k = 0; k < COND; k += 4) {
            float4 w  = *(const float4*)&wrow[k];
            float4 c4 = *(const float4*)&cs[k];
            acc = fmaf(w.x, c4.x, acc);
            acc = fmaf(w.y, c4.y, acc);
            acc = fmaf(w.z, c4.z, acc);
            acc = fmaf(w.w, c4.w, acc);
        }
        ss[o] = acc + bmap[o];
    }
    __syncthreads();
    for (int c = t; c < C_; c += 256) {
        int g = c >> 4;
        float mean = ws[OFF_STATS + (n * GRP + g) * 2];
        float rstd = ws[OFF_STATS + (n * GRP + g) * 2 + 1];
        float a = rstd * (ss[c] + 1.f);
        float b = ss[C_ + c] - mean * a;
        ws[OFF_A + n * C_ + c] = a;
        ws[OFF_B + n * C_ + c] = b;
    }
}

// ---------------- 3. QKV GEMM: qkv[n][o][p] = sum_c Wq[o][c]*(x[n][c][p]*a+b) + bq[o] ----------------
#define BM 128
#define BN 128
#define BK 16

__global__ __launch_bounds__(256) void qkv_gemm(const float* __restrict__ x,
                                                const float* __restrict__ Wq,
                                                const float* __restrict__ bq,
                                                float* __restrict__ ws) {
    int n  = blockIdx.z;
    int m0 = blockIdx.y * BM;   // over O3=1536
    int p0 = blockIdx.x * BN;   // over HW_=1024
    __shared__ float As[BK][BM];
    __shared__ float Bs[BK][BN];
    int t = threadIdx.x;
    int tm = t >> 4, tn = t & 15;
    const float* aA = ws + OFF_A + n * C_;
    const float* bA = ws + OFF_B + n * C_;
    float acc[8][8];
#pragma unroll
    for (int i = 0; i < 8; ++i)
#pragma unroll
        for (int j = 0; j < 8; ++j) acc[i][j] = 0.f;

    int ar = t >> 1;            // 0..127
    int ak = (t & 1) * 8;       // 0 or 8

    for (int k0 = 0; k0 < C_; k0 += BK) {
        // stage A (W_qkv tile, transposed to k-major)
        {
            const float* src = Wq + (size_t)(m0 + ar) * C_ + k0 + ak;
            float4 v0 = *(const float4*)src;
            float4 v1 = *(const float4*)(src + 4);
            As[ak + 0][ar] = v0.x; As[ak + 1][ar] = v0.y;
            As[ak + 2][ar] = v0.z; As[ak + 3][ar] = v0.w;
            As[ak + 4][ar] = v1.x; As[ak + 5][ar] = v1.y;
            As[ak + 6][ar] = v1.z; As[ak + 7][ar] = v1.w;
        }
        // stage B (input tile with groupnorm affine applied)
#pragma unroll
        for (int i = t; i < BK * BN / 4; i += 256) {
            int k = i >> 5, pv = i & 31;
            float av = aA[k0 + k], bv = bA[k0 + k];
            float4 v = *(const float4*)&x[((size_t)n * C_ + k0 + k) * HW_ + p0 + pv * 4];
            v.x = fmaf(v.x, av, bv); v.y = fmaf(v.y, av, bv);
            v.z = fmaf(v.z, av, bv); v.w = fmaf(v.w, av, bv);
            *(float4*)&Bs[k][pv * 4] = v;
        }
        __syncthreads();
#pragma unroll
        for (int kk = 0; kk < BK; ++kk) {
            float4 a0 = *(const float4*)&As[kk][tm * 8];
            float4 a1 = *(const float4*)&As[kk][tm * 8 + 4];
            float4 b0 = *(const float4*)&Bs[kk][tn * 8];
            float4 b1 = *(const float4*)&Bs[kk][tn * 8 + 4];
            float av[8] = {a0.x, a0.y, a0.z, a0.w, a1.x, a1.y, a1.z, a1.w};
            float bv[8] = {b0.x, b0.y, b0.z, b0.w, b1.x, b1.y, b1.z, b1.w};
#pragma unroll
            for (int i = 0; i < 8; ++i)
#pragma unroll
                for (int j = 0; j < 8; ++j)
                    acc[i][j] = fmaf(av[i], bv[j], acc[i][j]);
        }
        __syncthreads();
    }
    // epilogue: + b_qkv, store [n][o][p]
#pragma unroll
    for (int i = 0; i < 8; ++i) {
        int o = m0 + tm * 8 + i;
        float bias = bq[o];
        float* dst = ws + OFF_QKV + ((size_t)n * O3 + o) * HW_ + p0 + tn * 8;
        float4 o0 = make_float4(acc[i][0] + bias, acc[i][1] + bias,
                                acc[i][2] + bias, acc[i][3] + bias);
        float4 o1 = make_float4(acc[i][4] + bias, acc[i][5] + bias,
                                acc[i][6] + bias, acc[i][7] + bias);
        *(float4*)dst = o0;
        *(float4*)(dst + 4) = o1;
    }
}

// ---------------- 4. flash attention, 64 q-rows per block ----------------
__global__ __launch_bounds__(256) void attn_kernel(const float* __restrict__ qkv,
                                                   float* __restrict__ yout) {
    int q0 = blockIdx.x * 64;
    int h  = blockIdx.y;
    int n  = blockIdx.z;
    const float* qb = qkv + ((size_t)n * O3 + h * DH) * HW_;
    const float* kb = qb + (size_t)C_ * HW_;
    const float* vb = qb + (size_t)2 * C_ * HW_;

    __shared__ float Qs[64][64];       // [di][qp], pre-scaled by 1/8
    __shared__ float KP[64][68];       // dual role: Ks[di][kp] then P^T[kp][qp]
    __shared__ float VsT[64][68];      // [kp][dv]

    int t = threadIdx.x, tm = t >> 4, tn = t & 15;

    for (int i = t; i < 1024; i += 256) {
        int di = i >> 4, pv = i & 15;
        float4 q4 = *(const float4*)&qb[(size_t)di * HW_ + q0 + pv * 4];
        q4.x *= 0.125f; q4.y *= 0.125f; q4.z *= 0.125f; q4.w *= 0.125f;  // s^2 = d^-0.5
        *(float4*)&Qs[di][pv * 4] = q4;
    }

    float m_i[4], l_i[4], acc[4][4];
#pragma unroll
    for (int i = 0; i < 4; ++i) {
        m_i[i] = -1e30f; l_i[i] = 0.f;
#pragma unroll
        for (int j = 0; j < 4; ++j) acc[i][j] = 0.f;
    }
    __syncthreads();

    for (int kt = 0; kt < 16; ++kt) {
        const int k0 = kt * 64;
        // stage K and V^T
#pragma unroll
        for (int i = t; i < 1024; i += 256) {
            int dv = i >> 4, pv = i & 15;
            *(float4*)&KP[dv][pv * 4] = *(const float4*)&kb[(size_t)dv * HW_ + k0 + pv * 4];
            float4 vv = *(const float4*)&vb[(size_t)dv * HW_ + k0 + pv * 4];
            VsT[pv * 4 + 0][dv] = vv.x;
            VsT[pv * 4 + 1][dv] = vv.y;
            VsT[pv * 4 + 2][dv] = vv.z;
            VsT[pv * 4 + 3][dv] = vv.w;
        }
        __syncthreads();
        // S[qp][kp] = sum_di Qs[di][qp]*Ks[di][kp]
        float s[4][4];
#pragma unroll
        for (int i = 0; i < 4; ++i)
#pragma unroll
            for (int j = 0; j < 4; ++j) s[i][j] = 0.f;
#pragma unroll 8
        for (int di = 0; di < 64; ++di) {
            float4 q4 = *(const float4*)&Qs[di][tm * 4];
            float4 k4 = *(const float4*)&KP[di][tn * 4];
            float qa[4] = {q4.x, q4.y, q4.z, q4.w};
            float ka[4] = {k4.x, k4.y, k4.z, k4.w};
#pragma unroll
            for (int i = 0; i < 4; ++i)
#pragma unroll
                for (int j = 0; j < 4; ++j)
                    s[i][j] = fmaf(qa[i], ka[j], s[i][j]);
        }
        __syncthreads();   // S-phase reads of KP done; safe to overwrite with P^T
        // online softmax (rows split across tn lanes, low-4-bit shuffles)
#pragma unroll
        for (int i = 0; i < 4; ++i) {
            float rm = fmaxf(fmaxf(s[i][0], s[i][1]), fmaxf(s[i][2], s[i][3]));
            rm = fmaxf(rm, __shfl_xor(rm, 1));
            rm = fmaxf(rm, __shfl_xor(rm, 2));
            rm = fmaxf(rm, __shfl_xor(rm, 4));
            rm = fmaxf(rm, __shfl_xor(rm, 8));
            float nm = fmaxf(m_i[i], rm);
            float f  = __expf(m_i[i] - nm);
            float rs = 0.f;
#pragma unroll
            for (int j = 0; j < 4; ++j) {
                s[i][j] = __expf(s[i][j] - nm);
                rs += s[i][j];
            }
            rs += __shfl_xor(rs, 1);
            rs += __shfl_xor(rs, 2);
            rs += __shfl_xor(rs, 4);
            rs += __shfl_xor(rs, 8);
            l_i[i] = l_i[i] * f + rs;
            m_i[i] = nm;
#pragma unroll
            for (int j = 0; j < 4; ++j) acc[i][j] *= f;
            // write P^T[kp][qp]
#pragma unroll
            for (int j = 0; j < 4; ++j) KP[tn * 4 + j][tm * 4 + i] = s[i][j];
        }
        __syncthreads();
        // O[qp][dv] += sum_kp P^T[kp][qp] * V^T[kp][dv]
#pragma unroll 8
        for (int kp = 0; kp < 64; ++kp) {
            float4 p4 = *(const float4*)&KP[kp][tm * 4];
            float4 v4 = *(const float4*)&VsT[kp][tn * 4];
            float pa[4] = {p4.x, p4.y, p4.z, p4.w};
            float va[4] = {v4.x, v4.y, v4.z, v4.w};
#pragma unroll
            for (int i = 0; i < 4; ++i)
#pragma unroll
                for (int j = 0; j < 4; ++j)
                    acc[i][j] = fmaf(pa[i], va[j], acc[i][j]);
        }
        __syncthreads();   // PV reads done before next stage overwrites KP/VsT
    }
    // normalize and transpose O into KP: [dv][qp]
#pragma unroll
    for (int i = 0; i < 4; ++i) {
        float inv = 1.f / l_i[i];
#pragma unroll
        for (int j = 0; j < 4; ++j)
            KP[tn * 4 + j][tm * 4 + i] = acc[i][j] * inv;
    }
    __syncthreads();
    for (int idx = t; idx < 4096; idx += 256) {
        int dv = idx >> 6, qp = idx & 63;
        yout[((size_t)n * C_ + h * DH + dv) * HW_ + q0 + qp] = KP[dv][qp];
    }
}

// ---------------- 5. out-proj GEMM + bias + residual ----------------
__global__ __launch_bounds__(256) void out_gemm(const float* __restrict__ inp,
                                                const float* __restrict__ Wout,
                                                const float* __restrict__ bout,
                                                const float* __restrict__ ws,
                                                float* __restrict__ out) {
    int n  = blockIdx.z;
    int m0 = blockIdx.y * BM;   // over C_=512
    int p0 = blockIdx.x * BN;   // over HW_
    __shared__ float As[BK][BM];
    __shared__ float Bs[BK][BN];
    int t = threadIdx.x;
    int tm = t >> 4, tn = t & 15;
    const float* y = ws + OFF_Y + (size_t)n * C_ * HW_;
    float acc[8][8];
#pragma unroll
    for (int i = 0; i < 8; ++i)
#pragma unroll
        for (int j = 0; j < 8; ++j) acc[i][j] = 0.f;

    int ar = t >> 1;
    int ak = (t & 1) * 8;

    for (int k0 = 0; k0 < C_; k0 += BK) {
        {
            const float* src = Wout + (size_t)(m0 + ar) * C_ + k0 + ak;
            float4 v0 = *(const float4*)src;
            float4 v1 = *(const float4*)(src + 4);
            As[ak + 0][ar] = v0.x; As[ak + 1][ar] = v0.y;
            As[ak + 2][ar] = v0.z; As[ak + 3][ar] = v0.w;
            As[ak + 4][ar] = v1.x; As[ak + 5][ar] = v1.y;
            As[ak + 6][ar] = v1.z; As[ak + 7][ar] = v1.w;
        }
#pragma unroll
        for (int i = t; i < BK * BN / 4; i += 256) {
            int k = i >> 5, pv = i & 31;
            *(float4*)&Bs[k][pv * 4] = *(const float4*)&y[(size_t)(k0 + k) * HW_ + p0 + pv * 4];
        }
        __syncthreads();
#pragma unroll
        for (int kk = 0; kk < BK; ++kk) {
            float4 a0 = *(const float4*)&As[kk][tm * 8];
            float4 a1 = *(const float4*)&As[kk][tm * 8 + 4];
            float4 b0 = *(const float4*)&Bs[kk][tn * 8];
            float4 b1 = *(const float4*)&Bs[kk][tn * 8 + 4];
            float av[8] = {a0.x, a0.y, a0.z, a0.w, a1.x, a1.y, a1.z, a1.w};
            float bv[8] = {b0.x, b0.y, b0.z, b0.w, b1.x, b1.y, b1.z, b1.w};
#pragma unroll
            for (int i = 0; i < 8; ++i)
#pragma unroll
                for (int j = 0; j < 8; ++j)
                    acc[i][j] = fmaf(av[i], bv[j], acc[i][j]);
        }
        __syncthreads();
    }
#pragma unroll
    for (int i = 0; i < 8; ++i) {
        int o = m0 + tm * 8 + i;
        float bias = bout[o];
        size_t base = ((size_t)n * C_ + o) * HW_ + p0 + tn * 8;
        float4 i0 = *(const float4*)&inp[base];
        float4 i1 = *(const float4*)&inp[base + 4];
        float4 o0 = make_float4(acc[i][0] + bias + i0.x, acc[i][1] + bias + i0.y,
                                acc[i][2] + bias + i0.z, acc[i][3] + bias + i0.w);
        float4 o1 = make_float4(acc[i][4] + bias + i1.x, acc[i][5] + bias + i1.y,
                                acc[i][6] + bias + i1.z, acc[i][7] + bias + i1.w);
        *(float4*)&out[base]     = o0;
        *(float4*)&out[base + 4] = o1;
    }
}

extern "C" void kernel_launch(void* const* d_in, const int* in_sizes, int n_in,
                              void* d_out, int out_size, void* d_ws, size_t ws_size,
                              hipStream_t stream) {
    const float* input = (const float*)d_in[0];
    const float* cond  = (const float*)d_in[1];
    const float* Wqkv  = (const float*)d_in[2];
    const float* bqkv  = (const float*)d_in[3];
    const float* Wout  = (const float*)d_in[4];
    const float* bout  = (const float*)d_in[5];
    const float* Wmap  = (const float*)d_in[6];
    const float* bmap  = (const float*)d_in[7];
    float* ws  = (float*)d_ws;   // needs ~67.2 MB
    float* out = (float*)d_out;

    stats_kernel<<<dim3(B_ * GRP), 256, 0, stream>>>(input, ws);
    map_kernel<<<dim3(B_), 256, 0, stream>>>(cond, Wmap, bmap, ws);
    qkv_gemm<<<dim3(HW_ / BN, O3 / BM, B_), 256, 0, stream>>>(input, Wqkv, bqkv, ws);
    attn_kernel<<<dim3(HW_ / 64, NHEAD, B_), 256, 0, stream>>>(ws + OFF_QKV, ws + OFF_Y);
    out_gemm<<<dim3(HW_ / BN, C_ / BM, B_), 256, 0, stream>>>(input, Wout, bout, ws, out);
}

// Round 2
// 323.072 us; speedup vs baseline: 2.0825x; 2.0825x over previous
//
#include <hip/hip_runtime.h>
#include <cstddef>
#include <cstdint>

typedef unsigned short u16;
typedef unsigned int   u32;
typedef short bf16x8 __attribute__((ext_vector_type(8)));
typedef float f32x4  __attribute__((ext_vector_type(4)));

#define B_    8
#define C_    512
#define HW_   1024
#define NHEAD 8
#define DH    64
#define GRP   32
#define CPG   16
#define O3    1536
#define COND  512
#define EPSV  1e-5f

// ---- workspace byte offsets ----
#define BO_STATS 0x0u        // 512 f32
#define BO_AFFA  0x1000u     // 4096 f32
#define BO_AFFB  0x5000u     // 4096 f32
#define BO_WQ    0x10000u    // 786432 bf16
#define BO_WO    0x190000u   // 262144 bf16
#define BO_XT    0x210000u   // [n][p][c] bf16, 8MB
#define BO_Q     0xA10000u   // [n][h][p][d] bf16 (pre-scaled by 0.125)
#define BO_K     0x1210000u  // [n][h][p][d] bf16
#define BO_V     0x1A10000u  // [n][h][d][p] bf16
#define BO_Y     0x2210000u  // [n][p][c] bf16
// total 0x2A10000 = 44.1 MB (< 67MB proven available)

__device__ __forceinline__ u16 f2bf(float f) {
    u32 u = __float_as_uint(f);
    u += 0x7FFFu + ((u >> 16) & 1u);
    return (u16)(u >> 16);
}
__device__ __forceinline__ bf16x8 as_frag(uint4 v) {
    union { uint4 u; bf16x8 f; } c; c.u = v; return c.f;
}

// ---------------- 1. GroupNorm statistics ----------------
__global__ __launch_bounds__(256) void stats_kernel(const float* __restrict__ x,
                                                    float* __restrict__ stats) {
    int bid = blockIdx.x;            // n*GRP + g
    int n = bid >> 5, g = bid & 31;
    const float4* base = (const float4*)(x + ((size_t)n * C_ + g * CPG) * HW_);
    float s1 = 0.f, s2 = 0.f;
    for (int i = threadIdx.x; i < CPG * HW_ / 4; i += 256) {
        float4 v = base[i];
        s1 += v.x + v.y + v.z + v.w;
        s2 += v.x*v.x + v.y*v.y + v.z*v.z + v.w*v.w;
    }
    __shared__ float r1[256], r2[256];
    r1[threadIdx.x] = s1; r2[threadIdx.x] = s2;
    __syncthreads();
    for (int s = 128; s > 0; s >>= 1) {
        if (threadIdx.x < s) {
            r1[threadIdx.x] += r1[threadIdx.x + s];
            r2[threadIdx.x] += r2[threadIdx.x + s];
        }
        __syncthreads();
    }
    if (threadIdx.x == 0) {
        const float inv = 1.f / (CPG * HW_);
        float mean = r1[0] * inv;
        float var  = r2[0] * inv - mean * mean;
        stats[bid * 2]     = mean;
        stats[bid * 2 + 1] = rsqrtf(var + EPSV);
    }
}

// ---------------- 2. cond map -> per-(n,c) affine ----------------
__global__ __launch_bounds__(256) void map_kernel(const float* __restrict__ cond,
                                                  const float* __restrict__ Wmap,
                                                  const float* __restrict__ bmap,
                                                  const float* __restrict__ stats,
                                                  float* __restrict__ affA,
                                                  float* __restrict__ affB) {
    int n = blockIdx.x;
    __shared__ float cs[COND];
    __shared__ float ss[2 * C_];
    int t = threadIdx.x;
    cs[t]       = cond[n * COND + t];
    cs[t + 256] = cond[n * COND + t + 256];
    __syncthreads();
    for (int o = t; o < 2 * C_; o += 256) {
        const float* wrow = Wmap + (size_t)o * COND;
        float acc = 0.f;
        for (int k = 0; k < COND; k += 4) {
            float4 wv = *(const float4*)&wrow[k];
            float4 c4 = *(const float4*)&cs[k];
            acc = fmaf(wv.x, c4.x, acc);
            acc = fmaf(wv.y, c4.y, acc);
            acc = fmaf(wv.z, c4.z, acc);
            acc = fmaf(wv.w, c4.w, acc);
        }
        ss[o] = acc + bmap[o];
    }
    __syncthreads();
    for (int c = t; c < C_; c += 256) {
        int g = c >> 4;
        float mean = stats[(n * GRP + g) * 2];
        float rstd = stats[(n * GRP + g) * 2 + 1];
        float a = rstd * (ss[c] + 1.f);
        float b = ss[C_ + c] - mean * a;
        affA[n * C_ + c] = a;
        affB[n * C_ + c] = b;
    }
}

// ---------------- 3. weight fp32 -> bf16 ----------------
__global__ __launch_bounds__(256) void wconv_kernel(const float* __restrict__ wq,
                                                    const float* __restrict__ wo,
                                                    u16* __restrict__ wqb,
                                                    u16* __restrict__ wob) {
    int idx = blockIdx.x * 256 + threadIdx.x;     // quad index; grid = 1024 blocks
    if (idx < 196608) {                            // 786432/4
        float4 v = ((const float4*)wq)[idx];
        uint2 o;
        o.x = (u32)f2bf(v.x) | ((u32)f2bf(v.y) << 16);
        o.y = (u32)f2bf(v.z) | ((u32)f2bf(v.w) << 16);
        ((uint2*)wqb)[idx] = o;
    } else {
        int j = idx - 196608;                      // < 65536
        float4 v = ((const float4*)wo)[j];
        uint2 o;
        o.x = (u32)f2bf(v.x) | ((u32)f2bf(v.y) << 16);
        o.y = (u32)f2bf(v.z) | ((u32)f2bf(v.w) << 16);
        ((uint2*)wob)[j] = o;
    }
}

// ---------------- 4. x -> normed-x^T bf16  [n][p][c] ----------------
__global__ __launch_bounds__(256) void xt_kernel(const float* __restrict__ x,
                                                 const float* __restrict__ affA,
                                                 const float* __restrict__ affB,
                                                 u16* __restrict__ xt) {
    __shared__ float ts[64][65];
    const int t = threadIdx.x;
    const int n = blockIdx.z, c0 = blockIdx.y * 64, p0 = blockIdx.x * 64;
    {
        int cl = t >> 2, pq = t & 3;
        int c = c0 + cl;
        float a = affA[n * C_ + c], b = affB[n * C_ + c];
        const float* src = x + ((size_t)n * C_ + c) * HW_ + p0 + pq * 16;
#pragma unroll
        for (int ii = 0; ii < 4; ++ii) {
            float4 v = *(const float4*)(src + ii * 4);
            ts[cl][pq * 16 + ii * 4 + 0] = fmaf(v.x, a, b);
            ts[cl][pq * 16 + ii * 4 + 1] = fmaf(v.y, a, b);
            ts[cl][pq * 16 + ii * 4 + 2] = fmaf(v.z, a, b);
            ts[cl][pq * 16 + ii * 4 + 3] = fmaf(v.w, a, b);
        }
    }
    __syncthreads();
    {
        int pl = t >> 2, cq = t & 3;
        u16 us[16];
#pragma unroll
        for (int r = 0; r < 16; ++r) us[r] = f2bf(ts[cq * 16 + r][pl]);
        uint4 v0, v1;
        v0.x = (u32)us[0]  | ((u32)us[1]  << 16);
        v0.y = (u32)us[2]  | ((u32)us[3]  << 16);
        v0.z = (u32)us[4]  | ((u32)us[5]  << 16);
        v0.w = (u32)us[6]  | ((u32)us[7]  << 16);
        v1.x = (u32)us[8]  | ((u32)us[9]  << 16);
        v1.y = (u32)us[10] | ((u32)us[11] << 16);
        v1.z = (u32)us[12] | ((u32)us[13] << 16);
        v1.w = (u32)us[14] | ((u32)us[15] << 16);
        u16* dst = xt + ((size_t)n * HW_ + p0 + pl) * C_ + c0 + cq * 16;
        *(uint4*)dst = v0;
        *(uint4*)(dst + 8) = v1;
    }
}

// ---------------- 5. QKV GEMM (MFMA, direct-fragment) ----------------
// D[o][p] = sum_c Wq[o][c] * xt[p][c];  Q/K -> [n][h][p][d], V -> [n][h][d][p]
__global__ __launch_bounds__(256) void qkv_mfma(const u16* __restrict__ wqb,
                                                const float* __restrict__ bq,
                                                const u16* __restrict__ xt,
                                                u16* __restrict__ Qb,
                                                u16* __restrict__ Kb,
                                                u16* __restrict__ Vb) {
    __shared__ __attribute__((aligned(16))) u16 tb[4][64][80];  // [wave][p][o+pad]
    const int t = threadIdx.x, lane = t & 63, w = t >> 6;
    const int wm = w >> 1, wn = w & 1;
    const int lr = lane & 15, lg = lane >> 4;
    const int n = blockIdx.z;
    const int obase = blockIdx.y * 128 + wm * 64;   // 64-aligned -> single head/region per wave
    const int pbase = blockIdx.x * 128 + wn * 64;
    const uint4* A4 = (const uint4*)wqb;            // [o][c/8]
    const uint4* B4 = (const uint4*)xt;             // [n*HW+p][c/8]

    f32x4 acc[4][4] = {};
    int oa[4], pb[4];
#pragma unroll
    for (int f = 0; f < 4; ++f) {
        oa[f] = obase + f * 16 + lr;
        pb[f] = n * HW_ + pbase + f * 16 + lr;
    }

    for (int k8 = 0; k8 < 64; k8 += 4) {   // c0 = k8*8, step 32
        bf16x8 af[4], bfv[4];
#pragma unroll
        for (int f = 0; f < 4; ++f) af[f]  = as_frag(A4[oa[f] * 64 + lg + k8]);
#pragma unroll
        for (int f = 0; f < 4; ++f) bfv[f] = as_frag(B4[pb[f] * 64 + lg + k8]);
#pragma unroll
        for (int i = 0; i < 4; ++i)
#pragma unroll
            for (int j = 0; j < 4; ++j)
                acc[i][j] = __builtin_amdgcn_mfma_f32_16x16x32_bf16(af[i], bfv[j], acc[i][j], 0, 0, 0);
    }

    const int region = obase >> 9;            // 0=Q 1=K 2=V
    const int hsel = (obase & 511) >> 6;
    float bias[4][4];
#pragma unroll
    for (int i = 0; i < 4; ++i)
#pragma unroll
        for (int r = 0; r < 4; ++r) bias[i][r] = bq[obase + i * 16 + lg * 4 + r];

    if (region < 2) {
        const float sc = (region == 0) ? 0.125f : 1.0f;  // fold s^2 into Q
        u16* dst = (region == 0) ? Qb : Kb;
#pragma unroll
        for (int i = 0; i < 4; ++i)
#pragma unroll
            for (int j = 0; j < 4; ++j) {
                uint2 v;
                v.x = (u32)f2bf((acc[i][j][0] + bias[i][0]) * sc) |
                      ((u32)f2bf((acc[i][j][1] + bias[i][1]) * sc) << 16);
                v.y = (u32)f2bf((acc[i][j][2] + bias[i][2]) * sc) |
                      ((u32)f2bf((acc[i][j][3] + bias[i][3]) * sc) << 16);
                *(uint2*)&tb[w][j * 16 + lr][i * 16 + lg * 4] = v;  // [p_local][o_local]
            }
        __syncthreads();
        const size_t gb = ((size_t)(n * NHEAD + hsel) * HW_ + pbase) * DH;
#pragma unroll
        for (int c = 0; c < 8; ++c) {
            uint4 v = *(const uint4*)&tb[w][lane][c * 8];
            *(uint4*)&dst[gb + (size_t)lane * DH + c * 8] = v;
        }
    } else {
#pragma unroll
        for (int i = 0; i < 4; ++i)
#pragma unroll
            for (int j = 0; j < 4; ++j) {
                int p = pbase + j * 16 + lr;
#pragma unroll
                for (int r = 0; r < 4; ++r) {
                    int d = i * 16 + lg * 4 + r;
                    Vb[((size_t)(n * NHEAD + hsel) * DH + d) * HW_ + p] =
                        f2bf(acc[i][j][r] + bias[i][r]);
                }
            }
    }
}

// ---------------- 6. flash attention (MFMA) ----------------
__global__ __launch_bounds__(256) void attn_mfma(const u16* __restrict__ Qb,
                                                 const u16* __restrict__ Kb,
                                                 const u16* __restrict__ Vb,
                                                 u16* __restrict__ Yb) {
    __shared__ __attribute__((aligned(16))) u16 Kt[2][64][64]; // [buf][k][d], chunk^(k&7) swz
    __shared__ __attribute__((aligned(16))) u16 Vt[2][64][64]; // [buf][dv][k], swz
    __shared__ __attribute__((aligned(16))) u16 Pb[4][16][64]; // per-wave [q][*], swz
    const int t = threadIdx.x, lane = t & 63, w = t >> 6;
    const int lr = lane & 15, lg = lane >> 4;
    const int q0 = blockIdx.x * 64;
    const int nh = blockIdx.z * NHEAD + blockIdx.y;
    const size_t base = (size_t)nh * (HW_ * DH);
    const int srow = lane >> 3, schk = (lane & 7) ^ srow;   // staging source swizzle

    // Q fragments direct from global (pre-scaled)
    bf16x8 qf[2];
    {
        const uint4* Q4 = (const uint4*)(Qb + base);
        int qrow = q0 + w * 16 + lr;
        qf[0] = as_frag(Q4[qrow * 8 + lg]);
        qf[1] = as_frag(Q4[qrow * 8 + lg + 4]);
    }

    auto stage = [&](int b, int k0) {
        for (int ii = 0; ii < 2; ++ii) {
            int rk = w * 16 + ii * 8;
            const u16* gk = Kb + base + (size_t)(k0 + rk + srow) * DH + schk * 8;
            __builtin_amdgcn_global_load_lds((const __attribute__((address_space(1))) void*)gk,
                                             (__attribute__((address_space(3))) void*)&Kt[b][rk][0],
                                             16, 0, 0);
            const u16* gv = Vb + base + (size_t)(rk + srow) * HW_ + k0 + schk * 8;
            __builtin_amdgcn_global_load_lds((const __attribute__((address_space(1))) void*)gv,
                                             (__attribute__((address_space(3))) void*)&Vt[b][rk][0],
                                             16, 0, 0);
        }
    };

    float m_i[4], l_i[4];
    f32x4 accy[4] = {};
#pragma unroll
    for (int j = 0; j < 4; ++j) { m_i[j] = -3e38f; l_i[j] = 0.f; }

    int buf = 0;
    stage(0, 0);
    for (int kt = 0; kt < 16; ++kt) {
        __syncthreads();                       // drains staging of buf (vmcnt0) + fences prev reads
        if (kt < 15) stage(buf ^ 1, (kt + 1) * 64);

        // S = Q K^T  (rows q, cols k)
        f32x4 s4[4] = {};
#pragma unroll
        for (int nf = 0; nf < 4; ++nf) {
#pragma unroll
            for (int ks = 0; ks < 2; ++ks) {
                int kl = nf * 16 + lr;
                int cd = lg + ks * 4;
                bf16x8 kf = as_frag(*(const uint4*)&Kt[buf][kl][(cd ^ (kl & 7)) * 8]);
                s4[nf] = __builtin_amdgcn_mfma_f32_16x16x32_bf16(qf[ks], kf, s4[nf], 0, 0, 0);
            }
        }
        // online softmax (row q = lg*4+j, replicated across the 16-lane group)
        float p[4][4];
#pragma unroll
        for (int j = 0; j < 4; ++j) {
            float rm = fmaxf(fmaxf(s4[0][j], s4[1][j]), fmaxf(s4[2][j], s4[3][j]));
            rm = fmaxf(rm, __shfl_xor(rm, 1));
            rm = fmaxf(rm, __shfl_xor(rm, 2));
            rm = fmaxf(rm, __shfl_xor(rm, 4));
            rm = fmaxf(rm, __shfl_xor(rm, 8));
            float nm = fmaxf(m_i[j], rm);
            float f = __expf(m_i[j] - nm);
            float rs = 0.f;
#pragma unroll
            for (int nf = 0; nf < 4; ++nf) { p[nf][j] = __expf(s4[nf][j] - nm); rs += p[nf][j]; }
            rs += __shfl_xor(rs, 1); rs += __shfl_xor(rs, 2);
            rs += __shfl_xor(rs, 4); rs += __shfl_xor(rs, 8);
            l_i[j] = l_i[j] * f + rs; m_i[j] = nm;
#pragma unroll
            for (int df = 0; df < 4; ++df) accy[df][j] *= f;
        }
        // P -> per-wave LDS (bf16 pairs, even lanes write b32, XOR-swizzled)
        {
            u32* pw = (u32*)&Pb[w][0][0];
#pragma unroll
            for (int nf = 0; nf < 4; ++nf)
#pragma unroll
                for (int j = 0; j < 4; ++j) {
                    float other = __shfl_xor(p[nf][j], 1);
                    if ((lane & 1) == 0) {
                        u32 v = (u32)f2bf(p[nf][j]) | ((u32)f2bf(other) << 16);
                        int q = lg * 4 + j, k = nf * 16 + lr;   // k even
                        pw[q * 32 + (((k >> 3) ^ (q & 7)) * 4) + ((k & 7) >> 1)] = v;
                    }
                }
        }
        // PV: accy += P * V
#pragma unroll
        for (int ks = 0; ks < 2; ++ks) {
            int cd = lg + ks * 4;
            bf16x8 pf = as_frag(*(const uint4*)&Pb[w][lr][(cd ^ (lr & 7)) * 8]);
#pragma unroll
            for (int df = 0; df < 4; ++df) {
                int dl = df * 16 + lr;
                bf16x8 vf = as_frag(*(const uint4*)&Vt[buf][dl][(cd ^ (dl & 7)) * 8]);
                accy[df] = __builtin_amdgcn_mfma_f32_16x16x32_bf16(pf, vf, accy[df], 0, 0, 0);
            }
        }
        buf ^= 1;
    }

    // epilogue: normalize, transpose via Pb[w], store y [n][p][c] bf16
    float inv[4];
#pragma unroll
    for (int j = 0; j < 4; ++j) inv[j] = 1.f / l_i[j];
    {
        u32* pw = (u32*)&Pb[w][0][0];
#pragma unroll
        for (int df = 0; df < 4; ++df)
#pragma unroll
            for (int j = 0; j < 4; ++j) {
                float v = accy[df][j] * inv[j];
                float other = __shfl_xor(v, 1);
                if ((lane & 1) == 0) {
                    u32 u = (u32)f2bf(v) | ((u32)f2bf(other) << 16);
                    int q = lg * 4 + j, d = df * 16 + lr;       // d even
                    pw[q * 32 + (((d >> 3) ^ (q & 7)) * 4) + ((d & 7) >> 1)] = u;
                }
            }
    }
    {
        int q = lr;
        int p = q0 + w * 16 + q;
#pragma unroll
        for (int half = 0; half < 2; ++half) {
            int cd = lg + half * 4;
            uint4 v = *(const uint4*)&Pb[w][q][(cd ^ (q & 7)) * 8];
            *(uint4*)&Yb[((size_t)(blockIdx.z * HW_ + p)) * C_ + blockIdx.y * DH + cd * 8] = v;
        }
    }
}

// ---------------- 7. out-proj GEMM (MFMA) + bias + residual ----------------
__global__ __launch_bounds__(256) void out_mfma(const u16* __restrict__ wob,
                                                const float* __restrict__ bo,
                                                const u16* __restrict__ yb,
                                                const float* __restrict__ inp,
                                                float* __restrict__ out) {
    const int t = threadIdx.x, lane = t & 63, w = t >> 6;
    const int wm = w >> 1, wn = w & 1, lr = lane & 15, lg = lane >> 4;
    const int n = blockIdx.z;
    const int obase = blockIdx.y * 128 + wm * 64;
    const int pbase = blockIdx.x * 128 + wn * 64;
    const uint4* A4 = (const uint4*)wob;   // [o][c/8]
    const uint4* B4 = (const uint4*)yb;    // [n*HW+p][c/8]
    f32x4 acc[4][4] = {};
    int oa[4], pb[4];
#pragma unroll
    for (int f = 0; f < 4; ++f) {
        oa[f] = obase + f * 16 + lr;
        pb[f] = n * HW_ + pbase + f * 16 + lr;
    }
    for (int k8 = 0; k8 < 64; k8 += 4) {
        bf16x8 af[4], bfv[4];
#pragma unroll
        for (int f = 0; f < 4; ++f) af[f]  = as_frag(A4[oa[f] * 64 + lg + k8]);
#pragma unroll
        for (int f = 0; f < 4; ++f) bfv[f] = as_frag(B4[pb[f] * 64 + lg + k8]);
#pragma unroll
        for (int i = 0; i < 4; ++i)
#pragma unroll
            for (int j = 0; j < 4; ++j)
                acc[i][j] = __builtin_amdgcn_mfma_f32_16x16x32_bf16(af[i], bfv[j], acc[i][j], 0, 0, 0);
    }
#pragma unroll
    for (int i = 0; i < 4; ++i)
#pragma unroll
        for (int r = 0; r < 4; ++r) {
            int o = obase + i * 16 + lg * 4 + r;
            float bias = bo[o];
#pragma unroll
            for (int j = 0; j < 4; ++j) {
                int p = pbase + j * 16 + lr;
                size_t idx = ((size_t)n * C_ + o) * HW_ + p;
                out[idx] = acc[i][j][r] + bias + inp[idx];
            }
        }
}

extern "C" void kernel_launch(void* const* d_in, const int* in_sizes, int n_in,
                              void* d_out, int out_size, void* d_ws, size_t ws_size,
                              hipStream_t stream) {
    const float* input = (const float*)d_in[0];
    const float* cond  = (const float*)d_in[1];
    const float* Wqkv  = (const float*)d_in[2];
    const float* bqkv  = (const float*)d_in[3];
    const float* Wout  = (const float*)d_in[4];
    const float* bout  = (const float*)d_in[5];
    const float* Wmap  = (const float*)d_in[6];
    const float* bmap  = (const float*)d_in[7];
    float* out = (float*)d_out;

    char* wsb = (char*)d_ws;
    float* stats = (float*)(wsb + BO_STATS);
    float* affA  = (float*)(wsb + BO_AFFA);
    float* affB  = (float*)(wsb + BO_AFFB);
    u16* wqb = (u16*)(wsb + BO_WQ);
    u16* wob = (u16*)(wsb + BO_WO);
    u16* xt  = (u16*)(wsb + BO_XT);
    u16* Qb  = (u16*)(wsb + BO_Q);
    u16* Kb  = (u16*)(wsb + BO_K);
    u16* Vb  = (u16*)(wsb + BO_V);
    u16* Yb  = (u16*)(wsb + BO_Y);

    stats_kernel<<<dim3(B_ * GRP), 256, 0, stream>>>(input, stats);
    map_kernel<<<dim3(B_), 256, 0, stream>>>(cond, Wmap, bmap, stats, affA, affB);
    wconv_kernel<<<dim3(1024), 256, 0, stream>>>(Wqkv, Wout, wqb, wob);
    xt_kernel<<<dim3(16, 8, 8), 256, 0, stream>>>(input, affA, affB, xt);
    qkv_mfma<<<dim3(8, 12, 8), 256, 0, stream>>>(wqb, bqkv, xt, Qb, Kb, Vb);
    attn_mfma<<<dim3(16, 8, 8), 256, 0, stream>>>(Qb, Kb, Vb, Yb);
    out_mfma<<<dim3(8, 4, 8), 256, 0, stream>>>(wob, bout, Yb, input, out);
}

// Round 3
// 278.520 us; speedup vs baseline: 2.4156x; 1.1600x over previous
//
#include <hip/hip_runtime.h>
#include <cstddef>
#include <cstdint>

typedef unsigned short u16;
typedef unsigned int   u32;
typedef short bf16x8 __attribute__((ext_vector_type(8)));
typedef float f32x4  __attribute__((ext_vector_type(4)));

#define B_    8
#define C_    512
#define HW_   1024
#define NHEAD 8
#define DH    64
#define GRP   32
#define CPG   16
#define O3    1536
#define COND  512
#define EPSV  1e-5f
#define LOG2E 1.4426950408889634f

// ---- workspace byte offsets ----
#define BO_STATS 0x0u        // 512 f32
#define BO_AFFA  0x1000u     // 4096 f32
#define BO_AFFB  0x5000u     // 4096 f32
#define BO_WQ    0x10000u    // 786432 bf16
#define BO_WO    0x190000u   // 262144 bf16
#define BO_XT    0x210000u   // [n][p][c] bf16, 8MB
#define BO_Q     0xA10000u   // [n][h][p][d] bf16 (pre-scaled by 0.125*log2e)
#define BO_K     0x1210000u  // [n][h][p][d] bf16
#define BO_V     0x1A10000u  // [n][h][d][p] bf16
#define BO_Y     0x2210000u  // [n][p][c] bf16

__device__ __forceinline__ u16 f2bf(float f) {
    u32 u = __float_as_uint(f);
    u += 0x7FFFu + ((u >> 16) & 1u);
    return (u16)(u >> 16);
}
__device__ __forceinline__ u32 cvtpk_bf16(float lo, float hi) {
    u32 r;
    asm("v_cvt_pk_bf16_f32 %0, %1, %2" : "=v"(r) : "v"(lo), "v"(hi));
    return r;
}
__device__ __forceinline__ bf16x8 as_frag(uint4 v) {
    union { uint4 u; bf16x8 f; } c; c.u = v; return c.f;
}

// ---------------- 1. GroupNorm statistics ----------------
__global__ __launch_bounds__(256) void stats_kernel(const float* __restrict__ x,
                                                    float* __restrict__ stats) {
    int bid = blockIdx.x;            // n*GRP + g
    int n = bid >> 5, g = bid & 31;
    const float4* base = (const float4*)(x + ((size_t)n * C_ + g * CPG) * HW_);
    float s1 = 0.f, s2 = 0.f;
    for (int i = threadIdx.x; i < CPG * HW_ / 4; i += 256) {
        float4 v = base[i];
        s1 += v.x + v.y + v.z + v.w;
        s2 += v.x*v.x + v.y*v.y + v.z*v.z + v.w*v.w;
    }
    __shared__ float r1[256], r2[256];
    r1[threadIdx.x] = s1; r2[threadIdx.x] = s2;
    __syncthreads();
    for (int s = 128; s > 0; s >>= 1) {
        if (threadIdx.x < s) {
            r1[threadIdx.x] += r1[threadIdx.x + s];
            r2[threadIdx.x] += r2[threadIdx.x + s];
        }
        __syncthreads();
    }
    if (threadIdx.x == 0) {
        const float inv = 1.f / (CPG * HW_);
        float mean = r1[0] * inv;
        float var  = r2[0] * inv - mean * mean;
        stats[bid * 2]     = mean;
        stats[bid * 2 + 1] = rsqrtf(var + EPSV);
    }
}

// ---------------- 2. cond map -> per-(n,c) affine ----------------
__global__ __launch_bounds__(256) void map_kernel(const float* __restrict__ cond,
                                                  const float* __restrict__ Wmap,
                                                  const float* __restrict__ bmap,
                                                  const float* __restrict__ stats,
                                                  float* __restrict__ affA,
                                                  float* __restrict__ affB) {
    int n = blockIdx.x;
    __shared__ float cs[COND];
    __shared__ float ss[2 * C_];
    int t = threadIdx.x;
    cs[t]       = cond[n * COND + t];
    cs[t + 256] = cond[n * COND + t + 256];
    __syncthreads();
    for (int o = t; o < 2 * C_; o += 256) {
        const float* wrow = Wmap + (size_t)o * COND;
        float acc = 0.f;
        for (int k = 0; k < COND; k += 4) {
            float4 wv = *(const float4*)&wrow[k];
            float4 c4 = *(const float4*)&cs[k];
            acc = fmaf(wv.x, c4.x, acc);
            acc = fmaf(wv.y, c4.y, acc);
            acc = fmaf(wv.z, c4.z, acc);
            acc = fmaf(wv.w, c4.w, acc);
        }
        ss[o] = acc + bmap[o];
    }
    __syncthreads();
    for (int c = t; c < C_; c += 256) {
        int g = c >> 4;
        float mean = stats[(n * GRP + g) * 2];
        float rstd = stats[(n * GRP + g) * 2 + 1];
        float a = rstd * (ss[c] + 1.f);
        float b = ss[C_ + c] - mean * a;
        affA[n * C_ + c] = a;
        affB[n * C_ + c] = b;
    }
}

// ---------------- 3. weight fp32 -> bf16 ----------------
__global__ __launch_bounds__(256) void wconv_kernel(const float* __restrict__ wq,
                                                    const float* __restrict__ wo,
                                                    u16* __restrict__ wqb,
                                                    u16* __restrict__ wob) {
    int idx = blockIdx.x * 256 + threadIdx.x;     // quad index; grid = 1024 blocks
    if (idx < 196608) {                            // 786432/4
        float4 v = ((const float4*)wq)[idx];
        uint2 o;
        o.x = (u32)f2bf(v.x) | ((u32)f2bf(v.y) << 16);
        o.y = (u32)f2bf(v.z) | ((u32)f2bf(v.w) << 16);
        ((uint2*)wqb)[idx] = o;
    } else {
        int j = idx - 196608;                      // < 65536
        float4 v = ((const float4*)wo)[j];
        uint2 o;
        o.x = (u32)f2bf(v.x) | ((u32)f2bf(v.y) << 16);
        o.y = (u32)f2bf(v.z) | ((u32)f2bf(v.w) << 16);
        ((uint2*)wob)[j] = o;
    }
}

// ---------------- 4. x -> normed-x^T bf16  [n][p][c] ----------------
__global__ __launch_bounds__(256) void xt_kernel(const float* __restrict__ x,
                                                 const float* __restrict__ affA,
                                                 const float* __restrict__ affB,
                                                 u16* __restrict__ xt) {
    __shared__ float ts[64][65];
    const int t = threadIdx.x;
    const int n = blockIdx.z, c0 = blockIdx.y * 64, p0 = blockIdx.x * 64;
    {
        int cl = t >> 2, pq = t & 3;
        int c = c0 + cl;
        float a = affA[n * C_ + c], b = affB[n * C_ + c];
        const float* src = x + ((size_t)n * C_ + c) * HW_ + p0 + pq * 16;
#pragma unroll
        for (int ii = 0; ii < 4; ++ii) {
            float4 v = *(const float4*)(src + ii * 4);
            ts[cl][pq * 16 + ii * 4 + 0] = fmaf(v.x, a, b);
            ts[cl][pq * 16 + ii * 4 + 1] = fmaf(v.y, a, b);
            ts[cl][pq * 16 + ii * 4 + 2] = fmaf(v.z, a, b);
            ts[cl][pq * 16 + ii * 4 + 3] = fmaf(v.w, a, b);
        }
    }
    __syncthreads();
    {
        int pl = t >> 2, cq = t & 3;
        u16 us[16];
#pragma unroll
        for (int r = 0; r < 16; ++r) us[r] = f2bf(ts[cq * 16 + r][pl]);
        uint4 v0, v1;
        v0.x = (u32)us[0]  | ((u32)us[1]  << 16);
        v0.y = (u32)us[2]  | ((u32)us[3]  << 16);
        v0.z = (u32)us[4]  | ((u32)us[5]  << 16);
        v0.w = (u32)us[6]  | ((u32)us[7]  << 16);
        v1.x = (u32)us[8]  | ((u32)us[9]  << 16);
        v1.y = (u32)us[10] | ((u32)us[11] << 16);
        v1.z = (u32)us[12] | ((u32)us[13] << 16);
        v1.w = (u32)us[14] | ((u32)us[15] << 16);
        u16* dst = xt + ((size_t)n * HW_ + p0 + pl) * C_ + c0 + cq * 16;
        *(uint4*)dst = v0;
        *(uint4*)(dst + 8) = v1;
    }
}

// ---------------- 5. QKV GEMM (MFMA, direct-fragment, reg double-buffer) ----------------
__global__ __launch_bounds__(256) void qkv_mfma(const u16* __restrict__ wqb,
                                                const float* __restrict__ bq,
                                                const u16* __restrict__ xt,
                                                u16* __restrict__ Qb,
                                                u16* __restrict__ Kb,
                                                u16* __restrict__ Vb) {
    __shared__ __attribute__((aligned(16))) u16 tb[4][64][80];  // [wave][p][o+pad]
    const int t = threadIdx.x, lane = t & 63, w = t >> 6;
    const int wm = w >> 1, wn = w & 1;
    const int lr = lane & 15, lg = lane >> 4;
    const int b = blockIdx.x;                       // 768, XCD-affine decode
    const int n  = b & 7;
    const int px = (b >> 3) & 7;
    const int oy = b >> 6;                          // 0..11
    const int obase = oy * 128 + wm * 64;
    const int pbase = px * 128 + wn * 64;
    const uint4* A4 = (const uint4*)wqb;            // [o][c/8]
    const uint4* B4 = (const uint4*)xt;             // [n*HW+p][c/8]

    f32x4 acc[4][4] = {};
    int oa[4], pb[4];
#pragma unroll
    for (int f = 0; f < 4; ++f) {
        oa[f] = obase + f * 16 + lr;
        pb[f] = n * HW_ + pbase + f * 16 + lr;
    }

    bf16x8 aA[4], bA[4], aB[4], bB[4];
#define QLOAD(AF, BF, K8)                                              \
    do {                                                               \
        _Pragma("unroll")                                              \
        for (int f = 0; f < 4; ++f) AF[f] = as_frag(A4[oa[f] * 64 + lg + (K8)]); \
        _Pragma("unroll")                                              \
        for (int f = 0; f < 4; ++f) BF[f] = as_frag(B4[pb[f] * 64 + lg + (K8)]); \
    } while (0)
#define QMFMA(AF, BF)                                                  \
    do {                                                               \
        _Pragma("unroll")                                              \
        for (int i = 0; i < 4; ++i)                                    \
            _Pragma("unroll")                                          \
            for (int j = 0; j < 4; ++j)                                \
                acc[i][j] = __builtin_amdgcn_mfma_f32_16x16x32_bf16(AF[i], BF[j], acc[i][j], 0, 0, 0); \
    } while (0)

    QLOAD(aA, bA, 0);
#pragma unroll
    for (int k8 = 0; k8 < 64; k8 += 8) {
        QLOAD(aB, bB, k8 + 4);
        QMFMA(aA, bA);
        if (k8 + 8 < 64) QLOAD(aA, bA, k8 + 8);
        QMFMA(aB, bB);
    }

    const int region = obase >> 9;            // 0=Q 1=K 2=V
    const int hsel = (obase & 511) >> 6;
    float bias[4][4];
#pragma unroll
    for (int i = 0; i < 4; ++i)
#pragma unroll
        for (int r = 0; r < 4; ++r) bias[i][r] = bq[obase + i * 16 + lg * 4 + r];

    if (region < 2) {
        const float sc = (region == 0) ? 0.125f * LOG2E : 1.0f;  // fold s^2*log2e into Q
        u16* dst = (region == 0) ? Qb : Kb;
#pragma unroll
        for (int i = 0; i < 4; ++i)
#pragma unroll
            for (int j = 0; j < 4; ++j) {
                uint2 v;
                v.x = (u32)f2bf((acc[i][j][0] + bias[i][0]) * sc) |
                      ((u32)f2bf((acc[i][j][1] + bias[i][1]) * sc) << 16);
                v.y = (u32)f2bf((acc[i][j][2] + bias[i][2]) * sc) |
                      ((u32)f2bf((acc[i][j][3] + bias[i][3]) * sc) << 16);
                *(uint2*)&tb[w][j * 16 + lr][i * 16 + lg * 4] = v;  // [p_local][o_local]
            }
        __syncthreads();
        const size_t gb = ((size_t)(n * NHEAD + hsel) * HW_ + pbase) * DH;
#pragma unroll
        for (int c = 0; c < 8; ++c) {
            uint4 v = *(const uint4*)&tb[w][lane][c * 8];
            *(uint4*)&dst[gb + (size_t)lane * DH + c * 8] = v;
        }
    } else {
#pragma unroll
        for (int i = 0; i < 4; ++i)
#pragma unroll
            for (int j = 0; j < 4; ++j) {
                int p = pbase + j * 16 + lr;
#pragma unroll
                for (int r = 0; r < 4; ++r) {
                    int d = i * 16 + lg * 4 + r;
                    Vb[((size_t)(n * NHEAD + hsel) * DH + d) * HW_ + p] =
                        f2bf(acc[i][j][r] + bias[i][r]);
                }
            }
    }
}

// ---------------- 6. flash attention (MFMA, swapped QK^T, lane-local softmax) ----------------
__global__ __launch_bounds__(256) void attn_mfma(const u16* __restrict__ Qb,
                                                 const u16* __restrict__ Kb,
                                                 const u16* __restrict__ Vb,
                                                 u16* __restrict__ Yb) {
    __shared__ __attribute__((aligned(16))) u16 Kt[2][64][64]; // [buf][k][d], chunk^(k&7)
    __shared__ __attribute__((aligned(16))) u16 Vt[2][64][64]; // [buf][d][k], chunk^(d&7)
    __shared__ __attribute__((aligned(16))) u16 Pt[4][32][64]; // per-wave [q][k], chunk^(q&7)
    const int t = threadIdx.x, lane = t & 63, w = t >> 6;
    const int lr = lane & 15, lg = lane >> 4;
    const int b = blockIdx.x;                      // 512, XCD-affine: nh fixed per XCD
    const int nh = (b & 7) * 8 + ((b >> 3) & 7);
    const int q0g = (b >> 6) * 128;
    const size_t base = (size_t)nh * (HW_ * DH);
    const int srow = lane >> 3, schk = (lane & 7) ^ srow;   // staging source swizzle

    // Q fragments (pre-scaled by s^2*log2e), 32 q-rows per wave
    bf16x8 qf[2][2];
    {
        const uint4* Q4 = (const uint4*)(Qb + base);
#pragma unroll
        for (int qb = 0; qb < 2; ++qb) {
            int qrow = q0g + w * 32 + qb * 16 + lr;
            qf[qb][0] = as_frag(Q4[qrow * 8 + lg]);
            qf[qb][1] = as_frag(Q4[qrow * 8 + 4 + lg]);
        }
    }

    auto stage = [&](int bb, int k0) {
#pragma unroll
        for (int ii = 0; ii < 2; ++ii) {
            int rk = w * 16 + ii * 8;
            const u16* gk = Kb + base + (size_t)(k0 + rk + srow) * DH + schk * 8;
            __builtin_amdgcn_global_load_lds((const __attribute__((address_space(1))) void*)gk,
                                             (__attribute__((address_space(3))) void*)&Kt[bb][rk][0],
                                             16, 0, 0);
            const u16* gv = Vb + base + (size_t)(rk + srow) * HW_ + k0 + schk * 8;
            __builtin_amdgcn_global_load_lds((const __attribute__((address_space(1))) void*)gv,
                                             (__attribute__((address_space(3))) void*)&Vt[bb][rk][0],
                                             16, 0, 0);
        }
    };

    float m_i[2] = {-3e38f, -3e38f}, l_i[2] = {0.f, 0.f};
    f32x4 accy[4][2] = {};

    int buf = 0;
    stage(0, 0);
    for (int kt = 0; kt < 16; ++kt) {
        __syncthreads();                       // drains staging of buf + fences prev reads
        if (kt < 15) stage(buf ^ 1, (kt + 1) * 64);

        // S^T = K Q^T : D[row=k_loc][col=q];  lane holds q=...+lr, k = nf*16+lg*4+r
        f32x4 st[4][2] = {};
#pragma unroll
        for (int nf = 0; nf < 4; ++nf) {
#pragma unroll
            for (int ks = 0; ks < 2; ++ks) {
                int kl = nf * 16 + lr;
                bf16x8 kf = as_frag(*(const uint4*)&Kt[buf][kl][(((ks * 4 + lg) ^ (kl & 7)) * 8)]);
                st[nf][0] = __builtin_amdgcn_mfma_f32_16x16x32_bf16(kf, qf[0][ks], st[nf][0], 0, 0, 0);
                st[nf][1] = __builtin_amdgcn_mfma_f32_16x16x32_bf16(kf, qf[1][ks], st[nf][1], 0, 0, 0);
            }
        }
        // lane-local softmax (exp2 domain), q = qb*16+lr
#pragma unroll
        for (int qb = 0; qb < 2; ++qb) {
            float x0 = fmaxf(fmaxf(st[0][qb][0], st[0][qb][1]), fmaxf(st[0][qb][2], st[0][qb][3]));
            float x1 = fmaxf(fmaxf(st[1][qb][0], st[1][qb][1]), fmaxf(st[1][qb][2], st[1][qb][3]));
            float x2 = fmaxf(fmaxf(st[2][qb][0], st[2][qb][1]), fmaxf(st[2][qb][2], st[2][qb][3]));
            float x3 = fmaxf(fmaxf(st[3][qb][0], st[3][qb][1]), fmaxf(st[3][qb][2], st[3][qb][3]));
            float rm = fmaxf(fmaxf(x0, x1), fmaxf(x2, x3));
            rm = fmaxf(rm, __shfl_xor(rm, 16));
            rm = fmaxf(rm, __shfl_xor(rm, 32));
            float nm = fmaxf(m_i[qb], rm);
            float fct = exp2f(m_i[qb] - nm);
            m_i[qb] = nm;
#pragma unroll
            for (int nf = 0; nf < 4; ++nf)
#pragma unroll
                for (int r = 0; r < 4; ++r) st[nf][qb][r] = exp2f(st[nf][qb][r] - nm);
            float s0 = (st[0][qb][0] + st[0][qb][1]) + (st[0][qb][2] + st[0][qb][3]);
            float s1 = (st[1][qb][0] + st[1][qb][1]) + (st[1][qb][2] + st[1][qb][3]);
            float s2 = (st[2][qb][0] + st[2][qb][1]) + (st[2][qb][2] + st[2][qb][3]);
            float s3 = (st[3][qb][0] + st[3][qb][1]) + (st[3][qb][2] + st[3][qb][3]);
            float rs = (s0 + s1) + (s2 + s3);
            rs += __shfl_xor(rs, 16);
            rs += __shfl_xor(rs, 32);
            l_i[qb] = l_i[qb] * fct + rs;
#pragma unroll
            for (int df = 0; df < 4; ++df)
#pragma unroll
                for (int r = 0; r < 4; ++r) accy[df][qb][r] *= fct;
            // pack P -> per-wave LDS, swizzled; k = nf*16+lg*4..+3
            {
                int q = qb * 16 + lr;
#pragma unroll
                for (int nf = 0; nf < 4; ++nf) {
                    u32 lo = cvtpk_bf16(st[nf][qb][0], st[nf][qb][1]);
                    u32 hi = cvtpk_bf16(st[nf][qb][2], st[nf][qb][3]);
                    int c = nf * 2 + (lg >> 1);
                    *(uint2*)&Pt[w][q][((c ^ (lr & 7)) * 8) + (lg & 1) * 4] = make_uint2(lo, hi);
                }
            }
        }
        // PV: Y^T[d][q] += V^T[d][k] P^T[k][q]
#pragma unroll
        for (int ks = 0; ks < 2; ++ks) {
            int slot = ((ks * 4 + lg) ^ (lr & 7)) * 8;
            bf16x8 pf0 = as_frag(*(const uint4*)&Pt[w][lr][slot]);
            bf16x8 pf1 = as_frag(*(const uint4*)&Pt[w][16 + lr][slot]);
#pragma unroll
            for (int df = 0; df < 4; ++df) {
                int dl = df * 16 + lr;
                bf16x8 vf = as_frag(*(const uint4*)&Vt[buf][dl][(((ks * 4 + lg) ^ (dl & 7)) * 8)]);
                accy[df][0] = __builtin_amdgcn_mfma_f32_16x16x32_bf16(vf, pf0, accy[df][0], 0, 0, 0);
                accy[df][1] = __builtin_amdgcn_mfma_f32_16x16x32_bf16(vf, pf1, accy[df][1], 0, 0, 0);
            }
        }
        buf ^= 1;
    }

    // epilogue: normalize, direct global write (lane holds d = df*16+lg*4..+3, q=...+lr)
    const int n = nh >> 3, h = nh & 7;
#pragma unroll
    for (int qb = 0; qb < 2; ++qb) {
        float inv = 1.f / l_i[qb];
        int p = q0g + w * 32 + qb * 16 + lr;
#pragma unroll
        for (int df = 0; df < 4; ++df) {
            u32 lo = cvtpk_bf16(accy[df][qb][0] * inv, accy[df][qb][1] * inv);
            u32 hi = cvtpk_bf16(accy[df][qb][2] * inv, accy[df][qb][3] * inv);
            *(uint2*)&Yb[((size_t)(n * HW_ + p)) * C_ + h * DH + df * 16 + lg * 4] =
                make_uint2(lo, hi);
        }
    }
}

// ---------------- 7. out-proj GEMM (MFMA) + bias + residual ----------------
__global__ __launch_bounds__(256) void out_mfma(const u16* __restrict__ wob,
                                                const float* __restrict__ bo,
                                                const u16* __restrict__ yb,
                                                const float* __restrict__ inp,
                                                float* __restrict__ out) {
    const int t = threadIdx.x, lane = t & 63, w = t >> 6;
    const int wm = w >> 1, wn = w & 1, lr = lane & 15, lg = lane >> 4;
    const int b = blockIdx.x;                    // 256, XCD-affine decode
    const int n  = b & 7;
    const int px = (b >> 3) & 7;
    const int oy = b >> 6;                       // 0..3
    const int obase = oy * 128 + wm * 64;
    const int pbase = px * 128 + wn * 64;
    const uint4* A4 = (const uint4*)wob;   // [o][c/8]
    const uint4* B4 = (const uint4*)yb;    // [n*HW+p][c/8]
    f32x4 acc[4][4] = {};
    int oa[4], pb[4];
#pragma unroll
    for (int f = 0; f < 4; ++f) {
        oa[f] = obase + f * 16 + lr;
        pb[f] = n * HW_ + pbase + f * 16 + lr;
    }
    bf16x8 aA[4], bA[4], aB[4], bB[4];
    QLOAD(aA, bA, 0);
#pragma unroll
    for (int k8 = 0; k8 < 64; k8 += 8) {
        QLOAD(aB, bB, k8 + 4);
        QMFMA(aA, bA);
        if (k8 + 8 < 64) QLOAD(aA, bA, k8 + 8);
        QMFMA(aB, bB);
    }
#pragma unroll
    for (int i = 0; i < 4; ++i)
#pragma unroll
        for (int r = 0; r < 4; ++r) {
            int o = obase + i * 16 + lg * 4 + r;
            float bias = bo[o];
#pragma unroll
            for (int j = 0; j < 4; ++j) {
                int p = pbase + j * 16 + lr;
                size_t idx = ((size_t)n * C_ + o) * HW_ + p;
                out[idx] = acc[i][j][r] + bias + inp[idx];
            }
        }
}

extern "C" void kernel_launch(void* const* d_in, const int* in_sizes, int n_in,
                              void* d_out, int out_size, void* d_ws, size_t ws_size,
                              hipStream_t stream) {
    const float* input = (const float*)d_in[0];
    const float* cond  = (const float*)d_in[1];
    const float* Wqkv  = (const float*)d_in[2];
    const float* bqkv  = (const float*)d_in[3];
    const float* Wout  = (const float*)d_in[4];
    const float* bout  = (const float*)d_in[5];
    const float* Wmap  = (const float*)d_in[6];
    const float* bmap  = (const float*)d_in[7];
    float* out = (float*)d_out;

    char* wsb = (char*)d_ws;
    float* stats = (float*)(wsb + BO_STATS);
    float* affA  = (float*)(wsb + BO_AFFA);
    float* affB  = (float*)(wsb + BO_AFFB);
    u16* wqb = (u16*)(wsb + BO_WQ);
    u16* wob = (u16*)(wsb + BO_WO);
    u16* xt  = (u16*)(wsb + BO_XT);
    u16* Qb  = (u16*)(wsb + BO_Q);
    u16* Kb  = (u16*)(wsb + BO_K);
    u16* Vb  = (u16*)(wsb + BO_V);
    u16* Yb  = (u16*)(wsb + BO_Y);

    stats_kernel<<<dim3(B_ * GRP), 256, 0, stream>>>(input, stats);
    map_kernel<<<dim3(B_), 256, 0, stream>>>(cond, Wmap, bmap, stats, affA, affB);
    wconv_kernel<<<dim3(1024), 256, 0, stream>>>(Wqkv, Wout, wqb, wob);
    xt_kernel<<<dim3(16, 8, 8), 256, 0, stream>>>(input, affA, affB, xt);
    qkv_mfma<<<dim3(768), 256, 0, stream>>>(wqb, bqkv, xt, Qb, Kb, Vb);
    attn_mfma<<<dim3(512), 256, 0, stream>>>(Qb, Kb, Vb, Yb);
    out_mfma<<<dim3(256), 256, 0, stream>>>(wob, bout, Yb, input, out);
}

// Round 4
// 223.755 us; speedup vs baseline: 3.0068x; 1.2448x over previous
//
#include <hip/hip_runtime.h>
#include <cstddef>
#include <cstdint>

typedef unsigned short u16;
typedef unsigned int   u32;
typedef short bf16x8 __attribute__((ext_vector_type(8)));
typedef float f32x4  __attribute__((ext_vector_type(4)));

#define B_    8
#define C_    512
#define HW_   1024
#define NHEAD 8
#define DH    64
#define GRP   32
#define CPG   16
#define O3    1536
#define COND  512
#define EPSV  1e-5f
#define LOG2E 1.4426950408889634f

// ---- workspace byte offsets ----
#define BO_STATS 0x0u        // 512 f32
#define BO_AFFA  0x1000u     // 4096 f32
#define BO_AFFB  0x5000u     // 4096 f32
#define BO_WQ    0x10000u    // 786432 bf16
#define BO_WO    0x190000u   // 262144 bf16
#define BO_XT    0x210000u   // [n][p][c] bf16, 8MB
#define BO_Q     0xA10000u   // [n][h][p][d] bf16 (pre-scaled by 0.125*log2e)
#define BO_K     0x1210000u  // [n][h][p][d] bf16
#define BO_V     0x1A10000u  // [n][h][d][p] bf16
#define BO_Y     0x2210000u  // [n][p][c] bf16

__device__ __forceinline__ u16 f2bf(float f) {
    u32 u = __float_as_uint(f);
    u += 0x7FFFu + ((u >> 16) & 1u);
    return (u16)(u >> 16);
}
__device__ __forceinline__ u32 cvtpk_bf16(float lo, float hi) {
    u32 r;
    asm("v_cvt_pk_bf16_f32 %0, %1, %2" : "=v"(r) : "v"(lo), "v"(hi));
    return r;
}
__device__ __forceinline__ bf16x8 as_frag(uint4 v) {
    union { uint4 u; bf16x8 f; } c; c.u = v; return c.f;
}

// ---------------- 1. GroupNorm statistics ----------------
__global__ __launch_bounds__(256) void stats_kernel(const float* __restrict__ x,
                                                    float* __restrict__ stats) {
    int bid = blockIdx.x;            // n*GRP + g
    int n = bid >> 5, g = bid & 31;
    const float4* base = (const float4*)(x + ((size_t)n * C_ + g * CPG) * HW_);
    float s1 = 0.f, s2 = 0.f;
    for (int i = threadIdx.x; i < CPG * HW_ / 4; i += 256) {
        float4 v = base[i];
        s1 += v.x + v.y + v.z + v.w;
        s2 += v.x*v.x + v.y*v.y + v.z*v.z + v.w*v.w;
    }
    __shared__ float r1[256], r2[256];
    r1[threadIdx.x] = s1; r2[threadIdx.x] = s2;
    __syncthreads();
    for (int s = 128; s > 0; s >>= 1) {
        if (threadIdx.x < s) {
            r1[threadIdx.x] += r1[threadIdx.x + s];
            r2[threadIdx.x] += r2[threadIdx.x + s];
        }
        __syncthreads();
    }
    if (threadIdx.x == 0) {
        const float inv = 1.f / (CPG * HW_);
        float mean = r1[0] * inv;
        float var  = r2[0] * inv - mean * mean;
        stats[bid * 2]     = mean;
        stats[bid * 2 + 1] = rsqrtf(var + EPSV);
    }
}

// ---------------- 2. cond map -> per-(n,c) affine (256 blocks, 8 thr/output) ----------------
__global__ __launch_bounds__(256) void map_kernel(const float* __restrict__ cond,
                                                  const float* __restrict__ Wmap,
                                                  const float* __restrict__ bmap,
                                                  const float* __restrict__ stats,
                                                  float* __restrict__ affA,
                                                  float* __restrict__ affB) {
    const int bid = blockIdx.x;              // 256: n = bid&7 (XCD-affine), chunk = bid>>3
    const int n = bid & 7, chunk = bid >> 3; // chunk == groupnorm group (16 ch each)
    const int c0 = chunk * 16;
    __shared__ float cs[COND];
    __shared__ float red[32];
    const int t = threadIdx.x;
    cs[t]       = cond[n * COND + t];
    cs[t + 256] = cond[n * COND + t + 256];
    __syncthreads();
    const int oi = t >> 3, part = t & 7;     // oi 0..31: [0,16)=scale ch, [16,32)=shift ch
    const int is_shift = oi >> 4, ci = oi & 15;
    const int row = is_shift * C_ + c0 + ci;
    const float* wrow = Wmap + (size_t)row * COND + part * 4;
    float acc = 0.f;
#pragma unroll
    for (int i = 0; i < 16; ++i) {
        float4 wv = *(const float4*)(wrow + i * 32);
        float4 c4 = *(const float4*)&cs[i * 32 + part * 4];
        acc = fmaf(wv.x, c4.x, acc);
        acc = fmaf(wv.y, c4.y, acc);
        acc = fmaf(wv.z, c4.z, acc);
        acc = fmaf(wv.w, c4.w, acc);
    }
    acc += __shfl_xor(acc, 1);
    acc += __shfl_xor(acc, 2);
    acc += __shfl_xor(acc, 4);
    if (part == 0) red[oi] = acc;
    __syncthreads();
    if (t < 16) {
        float scale = red[t]      + bmap[c0 + t];
        float shift = red[16 + t] + bmap[C_ + c0 + t];
        float mean = stats[(n * GRP + chunk) * 2];
        float rstd = stats[(n * GRP + chunk) * 2 + 1];
        float a = rstd * (scale + 1.f);
        float b = shift - mean * a;
        affA[n * C_ + c0 + t] = a;
        affB[n * C_ + c0 + t] = b;
    }
}

// ---------------- 3. weight fp32 -> bf16 ----------------
__global__ __launch_bounds__(256) void wconv_kernel(const float* __restrict__ wq,
                                                    const float* __restrict__ wo,
                                                    u16* __restrict__ wqb,
                                                    u16* __restrict__ wob) {
    int idx = blockIdx.x * 256 + threadIdx.x;     // quad index; grid = 1024 blocks
    if (idx < 196608) {                            // 786432/4
        float4 v = ((const float4*)wq)[idx];
        uint2 o;
        o.x = (u32)f2bf(v.x) | ((u32)f2bf(v.y) << 16);
        o.y = (u32)f2bf(v.z) | ((u32)f2bf(v.w) << 16);
        ((uint2*)wqb)[idx] = o;
    } else {
        int j = idx - 196608;                      // < 65536
        float4 v = ((const float4*)wo)[j];
        uint2 o;
        o.x = (u32)f2bf(v.x) | ((u32)f2bf(v.y) << 16);
        o.y = (u32)f2bf(v.z) | ((u32)f2bf(v.w) << 16);
        ((uint2*)wob)[j] = o;
    }
}

// ---------------- 4. x -> normed-x^T bf16  [n][p][c] ----------------
__global__ __launch_bounds__(256) void xt_kernel(const float* __restrict__ x,
                                                 const float* __restrict__ affA,
                                                 const float* __restrict__ affB,
                                                 u16* __restrict__ xt) {
    __shared__ float ts[64][65];
    const int t = threadIdx.x;
    const int n = blockIdx.z, c0 = blockIdx.y * 64, p0 = blockIdx.x * 64;
    {
        int cl = t >> 2, pq = t & 3;
        int c = c0 + cl;
        float a = affA[n * C_ + c], b = affB[n * C_ + c];
        const float* src = x + ((size_t)n * C_ + c) * HW_ + p0 + pq * 16;
#pragma unroll
        for (int ii = 0; ii < 4; ++ii) {
            float4 v = *(const float4*)(src + ii * 4);
            ts[cl][pq * 16 + ii * 4 + 0] = fmaf(v.x, a, b);
            ts[cl][pq * 16 + ii * 4 + 1] = fmaf(v.y, a, b);
            ts[cl][pq * 16 + ii * 4 + 2] = fmaf(v.z, a, b);
            ts[cl][pq * 16 + ii * 4 + 3] = fmaf(v.w, a, b);
        }
    }
    __syncthreads();
    {
        int pl = t >> 2, cq = t & 3;
        u16 us[16];
#pragma unroll
        for (int r = 0; r < 16; ++r) us[r] = f2bf(ts[cq * 16 + r][pl]);
        uint4 v0, v1;
        v0.x = (u32)us[0]  | ((u32)us[1]  << 16);
        v0.y = (u32)us[2]  | ((u32)us[3]  << 16);
        v0.z = (u32)us[4]  | ((u32)us[5]  << 16);
        v0.w = (u32)us[6]  | ((u32)us[7]  << 16);
        v1.x = (u32)us[8]  | ((u32)us[9]  << 16);
        v1.y = (u32)us[10] | ((u32)us[11] << 16);
        v1.z = (u32)us[12] | ((u32)us[13] << 16);
        v1.w = (u32)us[14] | ((u32)us[15] << 16);
        u16* dst = xt + ((size_t)n * HW_ + p0 + pl) * C_ + c0 + cq * 16;
        *(uint4*)dst = v0;
        *(uint4*)(dst + 8) = v1;
    }
}

// ---------------- 5. QKV GEMM (MFMA, direct-fragment, reg double-buffer) ----------------
__global__ __launch_bounds__(256) void qkv_mfma(const u16* __restrict__ wqb,
                                                const float* __restrict__ bq,
                                                const u16* __restrict__ xt,
                                                u16* __restrict__ Qb,
                                                u16* __restrict__ Kb,
                                                u16* __restrict__ Vb) {
    __shared__ __attribute__((aligned(16))) u16 tb[4][64][80];  // [wave][p][o+pad]
    const int t = threadIdx.x, lane = t & 63, w = t >> 6;
    const int wm = w >> 1, wn = w & 1;
    const int lr = lane & 15, lg = lane >> 4;
    const int b = blockIdx.x;                       // 768, XCD-affine decode
    const int n  = b & 7;
    const int px = (b >> 3) & 7;
    const int oy = b >> 6;                          // 0..11
    const int obase = oy * 128 + wm * 64;
    const int pbase = px * 128 + wn * 64;
    const uint4* A4 = (const uint4*)wqb;            // [o][c/8]
    const uint4* B4 = (const uint4*)xt;             // [n*HW+p][c/8]

    f32x4 acc[4][4] = {};
    int oa[4], pb[4];
#pragma unroll
    for (int f = 0; f < 4; ++f) {
        oa[f] = obase + f * 16 + lr;
        pb[f] = n * HW_ + pbase + f * 16 + lr;
    }

    bf16x8 aA[4], bA[4], aB[4], bB[4];
#define QLOAD(AF, BF, K8)                                              \
    do {                                                               \
        _Pragma("unroll")                                              \
        for (int f = 0; f < 4; ++f) AF[f] = as_frag(A4[oa[f] * 64 + lg + (K8)]); \
        _Pragma("unroll")                                              \
        for (int f = 0; f < 4; ++f) BF[f] = as_frag(B4[pb[f] * 64 + lg + (K8)]); \
    } while (0)
#define QMFMA(AF, BF)                                                  \
    do {                                                               \
        _Pragma("unroll")                                              \
        for (int i = 0; i < 4; ++i)                                    \
            _Pragma("unroll")                                          \
            for (int j = 0; j < 4; ++j)                                \
                acc[i][j] = __builtin_amdgcn_mfma_f32_16x16x32_bf16(AF[i], BF[j], acc[i][j], 0, 0, 0); \
    } while (0)

    QLOAD(aA, bA, 0);
#pragma unroll
    for (int k8 = 0; k8 < 64; k8 += 8) {
        QLOAD(aB, bB, k8 + 4);
        QMFMA(aA, bA);
        if (k8 + 8 < 64) QLOAD(aA, bA, k8 + 8);
        QMFMA(aB, bB);
    }

    const int region = obase >> 9;            // 0=Q 1=K 2=V
    const int hsel = (obase & 511) >> 6;
    float bias[4][4];
#pragma unroll
    for (int i = 0; i < 4; ++i)
#pragma unroll
        for (int r = 0; r < 4; ++r) bias[i][r] = bq[obase + i * 16 + lg * 4 + r];

    if (region < 2) {
        const float sc = (region == 0) ? 0.125f * LOG2E : 1.0f;  // fold s^2*log2e into Q
        u16* dst = (region == 0) ? Qb : Kb;
#pragma unroll
        for (int i = 0; i < 4; ++i)
#pragma unroll
            for (int j = 0; j < 4; ++j) {
                uint2 v;
                v.x = (u32)f2bf((acc[i][j][0] + bias[i][0]) * sc) |
                      ((u32)f2bf((acc[i][j][1] + bias[i][1]) * sc) << 16);
                v.y = (u32)f2bf((acc[i][j][2] + bias[i][2]) * sc) |
                      ((u32)f2bf((acc[i][j][3] + bias[i][3]) * sc) << 16);
                *(uint2*)&tb[w][j * 16 + lr][i * 16 + lg * 4] = v;  // [p_local][o_local]
            }
        __syncthreads();
        const size_t gb = ((size_t)(n * NHEAD + hsel) * HW_ + pbase) * DH;
#pragma unroll
        for (int c = 0; c < 8; ++c) {
            uint4 v = *(const uint4*)&tb[w][lane][c * 8];
            *(uint4*)&dst[gb + (size_t)lane * DH + c * 8] = v;
        }
    } else {
#pragma unroll
        for (int i = 0; i < 4; ++i)
#pragma unroll
            for (int j = 0; j < 4; ++j) {
                int p = pbase + j * 16 + lr;
#pragma unroll
                for (int r = 0; r < 4; ++r) {
                    int d = i * 16 + lg * 4 + r;
                    Vb[((size_t)(n * NHEAD + hsel) * DH + d) * HW_ + p] =
                        f2bf(acc[i][j][r] + bias[i][r]);
                }
            }
    }
}

// ---------------- 6. flash attention (MFMA, swapped QK^T, lane-local softmax) ----------------
__global__ __launch_bounds__(256) void attn_mfma(const u16* __restrict__ Qb,
                                                 const u16* __restrict__ Kb,
                                                 const u16* __restrict__ Vb,
                                                 u16* __restrict__ Yb) {
    __shared__ __attribute__((aligned(16))) u16 Kt[2][64][64]; // [buf][k][d], chunk^(k&7)
    __shared__ __attribute__((aligned(16))) u16 Vt[2][64][64]; // [buf][d][k], chunk^(d&7)
    __shared__ __attribute__((aligned(16))) u16 Pt[4][32][64]; // per-wave [q][k], chunk^(q&7)
    const int t = threadIdx.x, lane = t & 63, w = t >> 6;
    const int lr = lane & 15, lg = lane >> 4;
    const int b = blockIdx.x;                      // 512, XCD-affine: nh fixed per XCD
    const int nh = (b & 7) * 8 + ((b >> 3) & 7);
    const int q0g = (b >> 6) * 128;
    const size_t base = (size_t)nh * (HW_ * DH);
    const int srow = lane >> 3, schk = (lane & 7) ^ srow;   // staging source swizzle

    // Q fragments (pre-scaled by s^2*log2e), 32 q-rows per wave
    bf16x8 qf[2][2];
    {
        const uint4* Q4 = (const uint4*)(Qb + base);
#pragma unroll
        for (int qb = 0; qb < 2; ++qb) {
            int qrow = q0g + w * 32 + qb * 16 + lr;
            qf[qb][0] = as_frag(Q4[qrow * 8 + lg]);
            qf[qb][1] = as_frag(Q4[qrow * 8 + 4 + lg]);
        }
    }

    auto stage = [&](int bb, int k0) {
#pragma unroll
        for (int ii = 0; ii < 2; ++ii) {
            int rk = w * 16 + ii * 8;
            const u16* gk = Kb + base + (size_t)(k0 + rk + srow) * DH + schk * 8;
            __builtin_amdgcn_global_load_lds((const __attribute__((address_space(1))) void*)gk,
                                             (__attribute__((address_space(3))) void*)&Kt[bb][rk][0],
                                             16, 0, 0);
            const u16* gv = Vb + base + (size_t)(rk + srow) * HW_ + k0 + schk * 8;
            __builtin_amdgcn_global_load_lds((const __attribute__((address_space(1))) void*)gv,
                                             (__attribute__((address_space(3))) void*)&Vt[bb][rk][0],
                                             16, 0, 0);
        }
    };

    float m_i[2] = {-3e38f, -3e38f}, l_i[2] = {0.f, 0.f};
    f32x4 accy[4][2] = {};

    int buf = 0;
    stage(0, 0);
    for (int kt = 0; kt < 16; ++kt) {
        __syncthreads();                       // drains staging of buf + fences prev reads
        if (kt < 15) stage(buf ^ 1, (kt + 1) * 64);

        // S^T = K Q^T : D[row=k_loc][col=q];  lane holds q=...+lr, k = nf*16+lg*4+r
        f32x4 st[4][2] = {};
#pragma unroll
        for (int nf = 0; nf < 4; ++nf) {
#pragma unroll
            for (int ks = 0; ks < 2; ++ks) {
                int kl = nf * 16 + lr;
                bf16x8 kf = as_frag(*(const uint4*)&Kt[buf][kl][(((ks * 4 + lg) ^ (kl & 7)) * 8)]);
                st[nf][0] = __builtin_amdgcn_mfma_f32_16x16x32_bf16(kf, qf[0][ks], st[nf][0], 0, 0, 0);
                st[nf][1] = __builtin_amdgcn_mfma_f32_16x16x32_bf16(kf, qf[1][ks], st[nf][1], 0, 0, 0);
            }
        }
        // lane-local softmax (exp2 domain), q = qb*16+lr
#pragma unroll
        for (int qb = 0; qb < 2; ++qb) {
            float x0 = fmaxf(fmaxf(st[0][qb][0], st[0][qb][1]), fmaxf(st[0][qb][2], st[0][qb][3]));
            float x1 = fmaxf(fmaxf(st[1][qb][0], st[1][qb][1]), fmaxf(st[1][qb][2], st[1][qb][3]));
            float x2 = fmaxf(fmaxf(st[2][qb][0], st[2][qb][1]), fmaxf(st[2][qb][2], st[2][qb][3]));
            float x3 = fmaxf(fmaxf(st[3][qb][0], st[3][qb][1]), fmaxf(st[3][qb][2], st[3][qb][3]));
            float rm = fmaxf(fmaxf(x0, x1), fmaxf(x2, x3));
            rm = fmaxf(rm, __shfl_xor(rm, 16));
            rm = fmaxf(rm, __shfl_xor(rm, 32));
            float nm = fmaxf(m_i[qb], rm);
            float fct = exp2f(m_i[qb] - nm);
            m_i[qb] = nm;
#pragma unroll
            for (int nf = 0; nf < 4; ++nf)
#pragma unroll
                for (int r = 0; r < 4; ++r) st[nf][qb][r] = exp2f(st[nf][qb][r] - nm);
            float s0 = (st[0][qb][0] + st[0][qb][1]) + (st[0][qb][2] + st[0][qb][3]);
            float s1 = (st[1][qb][0] + st[1][qb][1]) + (st[1][qb][2] + st[1][qb][3]);
            float s2 = (st[2][qb][0] + st[2][qb][1]) + (st[2][qb][2] + st[2][qb][3]);
            float s3 = (st[3][qb][0] + st[3][qb][1]) + (st[3][qb][2] + st[3][qb][3]);
            float rs = (s0 + s1) + (s2 + s3);
            rs += __shfl_xor(rs, 16);
            rs += __shfl_xor(rs, 32);
            l_i[qb] = l_i[qb] * fct + rs;
#pragma unroll
            for (int df = 0; df < 4; ++df)
#pragma unroll
                for (int r = 0; r < 4; ++r) accy[df][qb][r] *= fct;
            // pack P -> per-wave LDS, swizzled; k = nf*16+lg*4..+3
            {
                int q = qb * 16 + lr;
#pragma unroll
                for (int nf = 0; nf < 4; ++nf) {
                    u32 lo = cvtpk_bf16(st[nf][qb][0], st[nf][qb][1]);
                    u32 hi = cvtpk_bf16(st[nf][qb][2], st[nf][qb][3]);
                    int c = nf * 2 + (lg >> 1);
                    *(uint2*)&Pt[w][q][((c ^ (lr & 7)) * 8) + (lg & 1) * 4] = make_uint2(lo, hi);
                }
            }
        }
        // PV: Y^T[d][q] += V^T[d][k] P^T[k][q]
#pragma unroll
        for (int ks = 0; ks < 2; ++ks) {
            int slot = ((ks * 4 + lg) ^ (lr & 7)) * 8;
            bf16x8 pf0 = as_frag(*(const uint4*)&Pt[w][lr][slot]);
            bf16x8 pf1 = as_frag(*(const uint4*)&Pt[w][16 + lr][slot]);
#pragma unroll
            for (int df = 0; df < 4; ++df) {
                int dl = df * 16 + lr;
                bf16x8 vf = as_frag(*(const uint4*)&Vt[buf][dl][(((ks * 4 + lg) ^ (dl & 7)) * 8)]);
                accy[df][0] = __builtin_amdgcn_mfma_f32_16x16x32_bf16(vf, pf0, accy[df][0], 0, 0, 0);
                accy[df][1] = __builtin_amdgcn_mfma_f32_16x16x32_bf16(vf, pf1, accy[df][1], 0, 0, 0);
            }
        }
        buf ^= 1;
    }

    // epilogue: normalize, direct global write (lane holds d = df*16+lg*4..+3, q=...+lr)
    const int n = nh >> 3, h = nh & 7;
#pragma unroll
    for (int qb = 0; qb < 2; ++qb) {
        float inv = 1.f / l_i[qb];
        int p = q0g + w * 32 + qb * 16 + lr;
#pragma unroll
        for (int df = 0; df < 4; ++df) {
            u32 lo = cvtpk_bf16(accy[df][qb][0] * inv, accy[df][qb][1] * inv);
            u32 hi = cvtpk_bf16(accy[df][qb][2] * inv, accy[df][qb][3] * inv);
            *(uint2*)&Yb[((size_t)(n * HW_ + p)) * C_ + h * DH + df * 16 + lg * 4] =
                make_uint2(lo, hi);
        }
    }
}

// ---------------- 7. out-proj GEMM (MFMA) + bias + residual ----------------
__global__ __launch_bounds__(256) void out_mfma(const u16* __restrict__ wob,
                                                const float* __restrict__ bo,
                                                const u16* __restrict__ yb,
                                                const float* __restrict__ inp,
                                                float* __restrict__ out) {
    const int t = threadIdx.x, lane = t & 63, w = t >> 6;
    const int wm = w >> 1, wn = w & 1, lr = lane & 15, lg = lane >> 4;
    const int b = blockIdx.x;                    // 256, XCD-affine decode
    const int n  = b & 7;
    const int px = (b >> 3) & 7;
    const int oy = b >> 6;                       // 0..3
    const int obase = oy * 128 + wm * 64;
    const int pbase = px * 128 + wn * 64;
    const uint4* A4 = (const uint4*)wob;   // [o][c/8]
    const uint4* B4 = (const uint4*)yb;    // [n*HW+p][c/8]
    f32x4 acc[4][4] = {};
    int oa[4], pb[4];
#pragma unroll
    for (int f = 0; f < 4; ++f) {
        oa[f] = obase + f * 16 + lr;
        pb[f] = n * HW_ + pbase + f * 16 + lr;
    }
    bf16x8 aA[4], bA[4], aB[4], bB[4];
    QLOAD(aA, bA, 0);
#pragma unroll
    for (int k8 = 0; k8 < 64; k8 += 8) {
        QLOAD(aB, bB, k8 + 4);
        QMFMA(aA, bA);
        if (k8 + 8 < 64) QLOAD(aA, bA, k8 + 8);
        QMFMA(aB, bB);
    }
#pragma unroll
    for (int i = 0; i < 4; ++i)
#pragma unroll
        for (int r = 0; r < 4; ++r) {
            int o = obase + i * 16 + lg * 4 + r;
            float bias = bo[o];
#pragma unroll
            for (int j = 0; j < 4; ++j) {
                int p = pbase + j * 16 + lr;
                size_t idx = ((size_t)n * C_ + o) * HW_ + p;
                out[idx] = acc[i][j][r] + bias + inp[idx];
            }
        }
}

extern "C" void kernel_launch(void* const* d_in, const int* in_sizes, int n_in,
                              void* d_out, int out_size, void* d_ws, size_t ws_size,
                              hipStream_t stream) {
    const float* input = (const float*)d_in[0];
    const float* cond  = (const float*)d_in[1];
    const float* Wqkv  = (const float*)d_in[2];
    const float* bqkv  = (const float*)d_in[3];
    const float* Wout  = (const float*)d_in[4];
    const float* bout  = (const float*)d_in[5];
    const float* Wmap  = (const float*)d_in[6];
    const float* bmap  = (const float*)d_in[7];
    float* out = (float*)d_out;

    char* wsb = (char*)d_ws;
    float* stats = (float*)(wsb + BO_STATS);
    float* affA  = (float*)(wsb + BO_AFFA);
    float* affB  = (float*)(wsb + BO_AFFB);
    u16* wqb = (u16*)(wsb + BO_WQ);
    u16* wob = (u16*)(wsb + BO_WO);
    u16* xt  = (u16*)(wsb + BO_XT);
    u16* Qb  = (u16*)(wsb + BO_Q);
    u16* Kb  = (u16*)(wsb + BO_K);
    u16* Vb  = (u16*)(wsb + BO_V);
    u16* Yb  = (u16*)(wsb + BO_Y);

    stats_kernel<<<dim3(B_ * GRP), 256, 0, stream>>>(input, stats);
    map_kernel<<<dim3(256), 256, 0, stream>>>(cond, Wmap, bmap, stats, affA, affB);
    wconv_kernel<<<dim3(1024), 256, 0, stream>>>(Wqkv, Wout, wqb, wob);
    xt_kernel<<<dim3(16, 8, 8), 256, 0, stream>>>(input, affA, affB, xt);
    qkv_mfma<<<dim3(768), 256, 0, stream>>>(wqb, bqkv, xt, Qb, Kb, Vb);
    attn_mfma<<<dim3(512), 256, 0, stream>>>(Qb, Kb, Vb, Yb);
    out_mfma<<<dim3(256), 256, 0, stream>>>(wob, bout, Yb, input, out);
}

// Round 5
// 188.314 us; speedup vs baseline: 3.5727x; 1.1882x over previous
//
#include <hip/hip_runtime.h>
#include <cstddef>
#include <cstdint>

typedef unsigned short u16;
typedef unsigned int   u32;
typedef short bf16x8 __attribute__((ext_vector_type(8)));
typedef float f32x4  __attribute__((ext_vector_type(4)));

#define B_    8
#define C_    512
#define HW_   1024
#define NHEAD 8
#define DH    64
#define GRP   32
#define CPG   16
#define O3    1536
#define COND  512
#define EPSV  1e-5f
#define LOG2E 1.4426950408889634f

// ---- workspace byte offsets ----
#define BO_STATS 0x0u        // 512 f32
#define BO_AFFA  0x1000u     // 4096 f32
#define BO_AFFB  0x5000u     // 4096 f32
#define BO_WQ    0x10000u    // 786432 bf16
#define BO_WO    0x190000u   // 262144 bf16
#define BO_XT    0x210000u   // [n][p][c] bf16, 8MB
#define BO_Q     0xA10000u   // [n][h][p][d] bf16 (pre-scaled by 0.125*log2e)
#define BO_K     0x1210000u  // [n][h][p][d] bf16
#define BO_V     0x1A10000u  // [n][h][d][p] bf16
#define BO_Y     0x2210000u  // [n][p][c] bf16

__device__ __forceinline__ u16 f2bf(float f) {
    u32 u = __float_as_uint(f);
    u += 0x7FFFu + ((u >> 16) & 1u);
    return (u16)(u >> 16);
}
__device__ __forceinline__ u32 cvtpk_bf16(float lo, float hi) {
    u32 r;
    asm("v_cvt_pk_bf16_f32 %0, %1, %2" : "=v"(r) : "v"(lo), "v"(hi));
    return r;
}
__device__ __forceinline__ bf16x8 as_frag(uint4 v) {
    union { uint4 u; bf16x8 f; } c; c.u = v; return c.f;
}

// ---------------- 1. GroupNorm statistics ----------------
__global__ __launch_bounds__(256) void stats_kernel(const float* __restrict__ x,
                                                    float* __restrict__ stats) {
    int bid = blockIdx.x;            // n*GRP + g
    int n = bid >> 5, g = bid & 31;
    const float4* base = (const float4*)(x + ((size_t)n * C_ + g * CPG) * HW_);
    float s1 = 0.f, s2 = 0.f;
    for (int i = threadIdx.x; i < CPG * HW_ / 4; i += 256) {
        float4 v = base[i];
        s1 += v.x + v.y + v.z + v.w;
        s2 += v.x*v.x + v.y*v.y + v.z*v.z + v.w*v.w;
    }
    __shared__ float r1[256], r2[256];
    r1[threadIdx.x] = s1; r2[threadIdx.x] = s2;
    __syncthreads();
    for (int s = 128; s > 0; s >>= 1) {
        if (threadIdx.x < s) {
            r1[threadIdx.x] += r1[threadIdx.x + s];
            r2[threadIdx.x] += r2[threadIdx.x + s];
        }
        __syncthreads();
    }
    if (threadIdx.x == 0) {
        const float inv = 1.f / (CPG * HW_);
        float mean = r1[0] * inv;
        float var  = r2[0] * inv - mean * mean;
        stats[bid * 2]     = mean;
        stats[bid * 2 + 1] = rsqrtf(var + EPSV);
    }
}

// ---------------- 2. cond map -> per-(n,c) affine (256 blocks, 8 thr/output) ----------------
__global__ __launch_bounds__(256) void map_kernel(const float* __restrict__ cond,
                                                  const float* __restrict__ Wmap,
                                                  const float* __restrict__ bmap,
                                                  const float* __restrict__ stats,
                                                  float* __restrict__ affA,
                                                  float* __restrict__ affB) {
    const int bid = blockIdx.x;              // 256: n = bid&7 (XCD-affine), chunk = bid>>3
    const int n = bid & 7, chunk = bid >> 3; // chunk == groupnorm group (16 ch each)
    const int c0 = chunk * 16;
    __shared__ float cs[COND];
    __shared__ float red[32];
    const int t = threadIdx.x;
    cs[t]       = cond[n * COND + t];
    cs[t + 256] = cond[n * COND + t + 256];
    __syncthreads();
    const int oi = t >> 3, part = t & 7;     // oi 0..31: [0,16)=scale ch, [16,32)=shift ch
    const int is_shift = oi >> 4, ci = oi & 15;
    const int row = is_shift * C_ + c0 + ci;
    const float* wrow = Wmap + (size_t)row * COND + part * 4;
    float acc = 0.f;
#pragma unroll
    for (int i = 0; i < 16; ++i) {
        float4 wv = *(const float4*)(wrow + i * 32);
        float4 c4 = *(const float4*)&cs[i * 32 + part * 4];
        acc = fmaf(wv.x, c4.x, acc);
        acc = fmaf(wv.y, c4.y, acc);
        acc = fmaf(wv.z, c4.z, acc);
        acc = fmaf(wv.w, c4.w, acc);
    }
    acc += __shfl_xor(acc, 1);
    acc += __shfl_xor(acc, 2);
    acc += __shfl_xor(acc, 4);
    if (part == 0) red[oi] = acc;
    __syncthreads();
    if (t < 16) {
        float scale = red[t]      + bmap[c0 + t];
        float shift = red[16 + t] + bmap[C_ + c0 + t];
        float mean = stats[(n * GRP + chunk) * 2];
        float rstd = stats[(n * GRP + chunk) * 2 + 1];
        float a = rstd * (scale + 1.f);
        float b = shift - mean * a;
        affA[n * C_ + c0 + t] = a;
        affB[n * C_ + c0 + t] = b;
    }
}

// ---------------- 3. weight fp32 -> bf16 ----------------
__global__ __launch_bounds__(256) void wconv_kernel(const float* __restrict__ wq,
                                                    const float* __restrict__ wo,
                                                    u16* __restrict__ wqb,
                                                    u16* __restrict__ wob) {
    int idx = blockIdx.x * 256 + threadIdx.x;     // quad index; grid = 1024 blocks
    if (idx < 196608) {                            // 786432/4
        float4 v = ((const float4*)wq)[idx];
        uint2 o;
        o.x = (u32)f2bf(v.x) | ((u32)f2bf(v.y) << 16);
        o.y = (u32)f2bf(v.z) | ((u32)f2bf(v.w) << 16);
        ((uint2*)wqb)[idx] = o;
    } else {
        int j = idx - 196608;                      // < 65536
        float4 v = ((const float4*)wo)[j];
        uint2 o;
        o.x = (u32)f2bf(v.x) | ((u32)f2bf(v.y) << 16);
        o.y = (u32)f2bf(v.z) | ((u32)f2bf(v.w) << 16);
        ((uint2*)wob)[j] = o;
    }
}

// ---------------- 4. x -> normed-x^T bf16  [n][p][c] ----------------
__global__ __launch_bounds__(256) void xt_kernel(const float* __restrict__ x,
                                                 const float* __restrict__ affA,
                                                 const float* __restrict__ affB,
                                                 u16* __restrict__ xt) {
    __shared__ float ts[64][65];
    const int t = threadIdx.x;
    const int n = blockIdx.z, c0 = blockIdx.y * 64, p0 = blockIdx.x * 64;
    {
        int cl = t >> 2, pq = t & 3;
        int c = c0 + cl;
        float a = affA[n * C_ + c], b = affB[n * C_ + c];
        const float* src = x + ((size_t)n * C_ + c) * HW_ + p0 + pq * 16;
#pragma unroll
        for (int ii = 0; ii < 4; ++ii) {
            float4 v = *(const float4*)(src + ii * 4);
            ts[cl][pq * 16 + ii * 4 + 0] = fmaf(v.x, a, b);
            ts[cl][pq * 16 + ii * 4 + 1] = fmaf(v.y, a, b);
            ts[cl][pq * 16 + ii * 4 + 2] = fmaf(v.z, a, b);
            ts[cl][pq * 16 + ii * 4 + 3] = fmaf(v.w, a, b);
        }
    }
    __syncthreads();
    {
        int pl = t >> 2, cq = t & 3;
        u16 us[16];
#pragma unroll
        for (int r = 0; r < 16; ++r) us[r] = f2bf(ts[cq * 16 + r][pl]);
        uint4 v0, v1;
        v0.x = (u32)us[0]  | ((u32)us[1]  << 16);
        v0.y = (u32)us[2]  | ((u32)us[3]  << 16);
        v0.z = (u32)us[4]  | ((u32)us[5]  << 16);
        v0.w = (u32)us[6]  | ((u32)us[7]  << 16);
        v1.x = (u32)us[8]  | ((u32)us[9]  << 16);
        v1.y = (u32)us[10] | ((u32)us[11] << 16);
        v1.z = (u32)us[12] | ((u32)us[13] << 16);
        v1.w = (u32)us[14] | ((u32)us[15] << 16);
        u16* dst = xt + ((size_t)n * HW_ + p0 + pl) * C_ + c0 + cq * 16;
        *(uint4*)dst = v0;
        *(uint4*)(dst + 8) = v1;
    }
}

// ---------------- 5. QKV GEMM (MFMA, LDS-staged via global_load_lds) ----------------
// A = wqb [o][c], B = xt [n*HW+p][c]; 128x128 tile, BK=64, swizzled chunks.
__global__ __launch_bounds__(256) void qkv_mfma(const u16* __restrict__ wqb,
                                                const float* __restrict__ bq,
                                                const u16* __restrict__ xt,
                                                u16* __restrict__ Qb,
                                                u16* __restrict__ Kb,
                                                u16* __restrict__ Vb) {
    __shared__ __attribute__((aligned(16))) char smem[40960];
    u16 (*As)[64] = (u16(*)[64])smem;                 // [128][64]
    u16 (*Bs)[64] = (u16(*)[64])(smem + 16384);       // [128][64]
    u16 (*tb)[64][80] = (u16(*)[64][80])smem;         // [4][64][80] (epilogue alias)

    const int t = threadIdx.x, lane = t & 63, w = t >> 6;
    const int wm = w >> 1, wn = w & 1;
    const int lr = lane & 15, lg = lane >> 4;
    const int b = blockIdx.x;                       // 768, XCD-affine decode
    const int n  = b & 7;
    const int px = (b >> 3) & 7;
    const int oy = b >> 6;                          // 0..11
    const int obase = oy * 128 + wm * 64;
    const int pbase = px * 128 + wn * 64;
    const int rsub = lane >> 3, csub = lane & 7;    // staging row / chunk
    const int schk = csub ^ rsub;                   // pre-swizzled source chunk

    f32x4 acc[4][4] = {};

    for (int k0 = 0; k0 < C_; k0 += 64) {
#pragma unroll
        for (int ii = 0; ii < 4; ++ii) {
            int rloc = w * 32 + ii * 8;             // 8 rows per call
            const u16* ga = wqb + (size_t)(oy * 128 + rloc + rsub) * C_ + k0 + schk * 8;
            __builtin_amdgcn_global_load_lds((const __attribute__((address_space(1))) void*)ga,
                                             (__attribute__((address_space(3))) void*)&As[rloc][0],
                                             16, 0, 0);
            const u16* gb = xt + (size_t)(n * HW_ + px * 128 + rloc + rsub) * C_ + k0 + schk * 8;
            __builtin_amdgcn_global_load_lds((const __attribute__((address_space(1))) void*)gb,
                                             (__attribute__((address_space(3))) void*)&Bs[rloc][0],
                                             16, 0, 0);
        }
        __syncthreads();                            // drains staging (vmcnt0) before reads
#pragma unroll
        for (int ks = 0; ks < 2; ++ks) {
            bf16x8 af[4], bfv[4];
#pragma unroll
            for (int f = 0; f < 4; ++f) {
                int ra = wm * 64 + f * 16 + lr;
                af[f] = as_frag(*(const uint4*)&As[ra][((ks * 4 + lg) ^ (ra & 7)) * 8]);
                int rb = wn * 64 + f * 16 + lr;
                bfv[f] = as_frag(*(const uint4*)&Bs[rb][((ks * 4 + lg) ^ (rb & 7)) * 8]);
            }
#pragma unroll
            for (int i = 0; i < 4; ++i)
#pragma unroll
                for (int j = 0; j < 4; ++j)
                    acc[i][j] = __builtin_amdgcn_mfma_f32_16x16x32_bf16(af[i], bfv[j], acc[i][j], 0, 0, 0);
        }
        __syncthreads();                            // reads done before next-tile staging
    }

    const int region = obase >> 9;            // 0=Q 1=K 2=V
    const int hsel = (obase & 511) >> 6;
    float bias[4][4];
#pragma unroll
    for (int i = 0; i < 4; ++i)
#pragma unroll
        for (int r = 0; r < 4; ++r) bias[i][r] = bq[obase + i * 16 + lg * 4 + r];

    if (region < 2) {
        const float sc = (region == 0) ? 0.125f * LOG2E : 1.0f;  // fold s^2*log2e into Q
        u16* dst = (region == 0) ? Qb : Kb;
#pragma unroll
        for (int i = 0; i < 4; ++i)
#pragma unroll
            for (int j = 0; j < 4; ++j) {
                uint2 v;
                v.x = (u32)f2bf((acc[i][j][0] + bias[i][0]) * sc) |
                      ((u32)f2bf((acc[i][j][1] + bias[i][1]) * sc) << 16);
                v.y = (u32)f2bf((acc[i][j][2] + bias[i][2]) * sc) |
                      ((u32)f2bf((acc[i][j][3] + bias[i][3]) * sc) << 16);
                *(uint2*)&tb[w][j * 16 + lr][i * 16 + lg * 4] = v;  // [p_local][o_local]
            }
        __syncthreads();
        const size_t gb = ((size_t)(n * NHEAD + hsel) * HW_ + pbase) * DH;
#pragma unroll
        for (int c = 0; c < 8; ++c) {
            uint4 v = *(const uint4*)&tb[w][lane][c * 8];
            *(uint4*)&dst[gb + (size_t)lane * DH + c * 8] = v;
        }
    } else {
#pragma unroll
        for (int i = 0; i < 4; ++i)
#pragma unroll
            for (int j = 0; j < 4; ++j) {
                int p = pbase + j * 16 + lr;
#pragma unroll
                for (int r = 0; r < 4; ++r) {
                    int d = i * 16 + lg * 4 + r;
                    Vb[((size_t)(n * NHEAD + hsel) * DH + d) * HW_ + p] =
                        f2bf(acc[i][j][r] + bias[i][r]);
                }
            }
    }
}

// ---------------- 6. flash attention (MFMA, swapped QK^T, lane-local softmax) ----------------
__global__ __launch_bounds__(256) void attn_mfma(const u16* __restrict__ Qb,
                                                 const u16* __restrict__ Kb,
                                                 const u16* __restrict__ Vb,
                                                 u16* __restrict__ Yb) {
    __shared__ __attribute__((aligned(16))) u16 Kt[2][64][64]; // [buf][k][d], chunk^(k&7)
    __shared__ __attribute__((aligned(16))) u16 Vt[2][64][64]; // [buf][d][k], chunk^(d&7)
    __shared__ __attribute__((aligned(16))) u16 Pt[4][32][64]; // per-wave [q][k], chunk^(q&7)
    const int t = threadIdx.x, lane = t & 63, w = t >> 6;
    const int lr = lane & 15, lg = lane >> 4;
    const int b = blockIdx.x;                      // 512, XCD-affine: nh fixed per XCD
    const int nh = (b & 7) * 8 + ((b >> 3) & 7);
    const int q0g = (b >> 6) * 128;
    const size_t base = (size_t)nh * (HW_ * DH);
    const int srow = lane >> 3, schk = (lane & 7) ^ srow;   // staging source swizzle

    // Q fragments (pre-scaled by s^2*log2e), 32 q-rows per wave
    bf16x8 qf[2][2];
    {
        const uint4* Q4 = (const uint4*)(Qb + base);
#pragma unroll
        for (int qb = 0; qb < 2; ++qb) {
            int qrow = q0g + w * 32 + qb * 16 + lr;
            qf[qb][0] = as_frag(Q4[qrow * 8 + lg]);
            qf[qb][1] = as_frag(Q4[qrow * 8 + 4 + lg]);
        }
    }

    auto stage = [&](int bb, int k0) {
#pragma unroll
        for (int ii = 0; ii < 2; ++ii) {
            int rk = w * 16 + ii * 8;
            const u16* gk = Kb + base + (size_t)(k0 + rk + srow) * DH + schk * 8;
            __builtin_amdgcn_global_load_lds((const __attribute__((address_space(1))) void*)gk,
                                             (__attribute__((address_space(3))) void*)&Kt[bb][rk][0],
                                             16, 0, 0);
            const u16* gv = Vb + base + (size_t)(rk + srow) * HW_ + k0 + schk * 8;
            __builtin_amdgcn_global_load_lds((const __attribute__((address_space(1))) void*)gv,
                                             (__attribute__((address_space(3))) void*)&Vt[bb][rk][0],
                                             16, 0, 0);
        }
    };

    float m_i[2] = {-3e38f, -3e38f}, l_i[2] = {0.f, 0.f};
    f32x4 accy[4][2] = {};

    int buf = 0;
    stage(0, 0);
    for (int kt = 0; kt < 16; ++kt) {
        __syncthreads();                       // drains staging of buf + fences prev reads
        if (kt < 15) stage(buf ^ 1, (kt + 1) * 64);

        // S^T = K Q^T : D[row=k_loc][col=q];  lane holds q=...+lr, k = nf*16+lg*4+r
        f32x4 st[4][2] = {};
#pragma unroll
        for (int nf = 0; nf < 4; ++nf) {
#pragma unroll
            for (int ks = 0; ks < 2; ++ks) {
                int kl = nf * 16 + lr;
                bf16x8 kf = as_frag(*(const uint4*)&Kt[buf][kl][(((ks * 4 + lg) ^ (kl & 7)) * 8)]);
                st[nf][0] = __builtin_amdgcn_mfma_f32_16x16x32_bf16(kf, qf[0][ks], st[nf][0], 0, 0, 0);
                st[nf][1] = __builtin_amdgcn_mfma_f32_16x16x32_bf16(kf, qf[1][ks], st[nf][1], 0, 0, 0);
            }
        }
        // lane-local softmax (exp2 domain), q = qb*16+lr
#pragma unroll
        for (int qb = 0; qb < 2; ++qb) {
            float x0 = fmaxf(fmaxf(st[0][qb][0], st[0][qb][1]), fmaxf(st[0][qb][2], st[0][qb][3]));
            float x1 = fmaxf(fmaxf(st[1][qb][0], st[1][qb][1]), fmaxf(st[1][qb][2], st[1][qb][3]));
            float x2 = fmaxf(fmaxf(st[2][qb][0], st[2][qb][1]), fmaxf(st[2][qb][2], st[2][qb][3]));
            float x3 = fmaxf(fmaxf(st[3][qb][0], st[3][qb][1]), fmaxf(st[3][qb][2], st[3][qb][3]));
            float rm = fmaxf(fmaxf(x0, x1), fmaxf(x2, x3));
            rm = fmaxf(rm, __shfl_xor(rm, 16));
            rm = fmaxf(rm, __shfl_xor(rm, 32));
            float nm = fmaxf(m_i[qb], rm);
            float fct = exp2f(m_i[qb] - nm);
            m_i[qb] = nm;
#pragma unroll
            for (int nf = 0; nf < 4; ++nf)
#pragma unroll
                for (int r = 0; r < 4; ++r) st[nf][qb][r] = exp2f(st[nf][qb][r] - nm);
            float s0 = (st[0][qb][0] + st[0][qb][1]) + (st[0][qb][2] + st[0][qb][3]);
            float s1 = (st[1][qb][0] + st[1][qb][1]) + (st[1][qb][2] + st[1][qb][3]);
            float s2 = (st[2][qb][0] + st[2][qb][1]) + (st[2][qb][2] + st[2][qb][3]);
            float s3 = (st[3][qb][0] + st[3][qb][1]) + (st[3][qb][2] + st[3][qb][3]);
            float rs = (s0 + s1) + (s2 + s3);
            rs += __shfl_xor(rs, 16);
            rs += __shfl_xor(rs, 32);
            l_i[qb] = l_i[qb] * fct + rs;
#pragma unroll
            for (int df = 0; df < 4; ++df)
#pragma unroll
                for (int r = 0; r < 4; ++r) accy[df][qb][r] *= fct;
            // pack P -> per-wave LDS, swizzled; k = nf*16+lg*4..+3
            {
                int q = qb * 16 + lr;
#pragma unroll
                for (int nf = 0; nf < 4; ++nf) {
                    u32 lo = cvtpk_bf16(st[nf][qb][0], st[nf][qb][1]);
                    u32 hi = cvtpk_bf16(st[nf][qb][2], st[nf][qb][3]);
                    int c = nf * 2 + (lg >> 1);
                    *(uint2*)&Pt[w][q][((c ^ (lr & 7)) * 8) + (lg & 1) * 4] = make_uint2(lo, hi);
                }
            }
        }
        // PV: Y^T[d][q] += V^T[d][k] P^T[k][q]
#pragma unroll
        for (int ks = 0; ks < 2; ++ks) {
            int slot = ((ks * 4 + lg) ^ (lr & 7)) * 8;
            bf16x8 pf0 = as_frag(*(const uint4*)&Pt[w][lr][slot]);
            bf16x8 pf1 = as_frag(*(const uint4*)&Pt[w][16 + lr][slot]);
#pragma unroll
            for (int df = 0; df < 4; ++df) {
                int dl = df * 16 + lr;
                bf16x8 vf = as_frag(*(const uint4*)&Vt[buf][dl][(((ks * 4 + lg) ^ (dl & 7)) * 8)]);
                accy[df][0] = __builtin_amdgcn_mfma_f32_16x16x32_bf16(vf, pf0, accy[df][0], 0, 0, 0);
                accy[df][1] = __builtin_amdgcn_mfma_f32_16x16x32_bf16(vf, pf1, accy[df][1], 0, 0, 0);
            }
        }
        buf ^= 1;
    }

    // epilogue: normalize, direct global write (lane holds d = df*16+lg*4..+3, q=...+lr)
    const int n = nh >> 3, h = nh & 7;
#pragma unroll
    for (int qb = 0; qb < 2; ++qb) {
        float inv = 1.f / l_i[qb];
        int p = q0g + w * 32 + qb * 16 + lr;
#pragma unroll
        for (int df = 0; df < 4; ++df) {
            u32 lo = cvtpk_bf16(accy[df][qb][0] * inv, accy[df][qb][1] * inv);
            u32 hi = cvtpk_bf16(accy[df][qb][2] * inv, accy[df][qb][3] * inv);
            *(uint2*)&Yb[((size_t)(n * HW_ + p)) * C_ + h * DH + df * 16 + lg * 4] =
                make_uint2(lo, hi);
        }
    }
}

// ---------------- 7. out-proj GEMM (MFMA, LDS-staged) + bias + residual ----------------
__global__ __launch_bounds__(256) void out_mfma(const u16* __restrict__ wob,
                                                const float* __restrict__ bo,
                                                const u16* __restrict__ yb,
                                                const float* __restrict__ inp,
                                                float* __restrict__ out) {
    __shared__ __attribute__((aligned(16))) u16 As[128][64];
    __shared__ __attribute__((aligned(16))) u16 Bs[128][64];
    const int t = threadIdx.x, lane = t & 63, w = t >> 6;
    const int wm = w >> 1, wn = w & 1, lr = lane & 15, lg = lane >> 4;
    const int b = blockIdx.x;                    // 256, XCD-affine decode
    const int n  = b & 7;
    const int px = (b >> 3) & 7;
    const int oy = b >> 6;                       // 0..3
    const int obase = oy * 128 + wm * 64;
    const int pbase = px * 128 + wn * 64;
    const int rsub = lane >> 3, csub = lane & 7;
    const int schk = csub ^ rsub;

    f32x4 acc[4][4] = {};

    for (int k0 = 0; k0 < C_; k0 += 64) {
#pragma unroll
        for (int ii = 0; ii < 4; ++ii) {
            int rloc = w * 32 + ii * 8;
            const u16* ga = wob + (size_t)(oy * 128 + rloc + rsub) * C_ + k0 + schk * 8;
            __builtin_amdgcn_global_load_lds((const __attribute__((address_space(1))) void*)ga,
                                             (__attribute__((address_space(3))) void*)&As[rloc][0],
                                             16, 0, 0);
            const u16* gb = yb + (size_t)(n * HW_ + px * 128 + rloc + rsub) * C_ + k0 + schk * 8;
            __builtin_amdgcn_global_load_lds((const __attribute__((address_space(1))) void*)gb,
                                             (__attribute__((address_space(3))) void*)&Bs[rloc][0],
                                             16, 0, 0);
        }
        __syncthreads();
#pragma unroll
        for (int ks = 0; ks < 2; ++ks) {
            bf16x8 af[4], bfv[4];
#pragma unroll
            for (int f = 0; f < 4; ++f) {
                int ra = wm * 64 + f * 16 + lr;
                af[f] = as_frag(*(const uint4*)&As[ra][((ks * 4 + lg) ^ (ra & 7)) * 8]);
                int rb = wn * 64 + f * 16 + lr;
                bfv[f] = as_frag(*(const uint4*)&Bs[rb][((ks * 4 + lg) ^ (rb & 7)) * 8]);
            }
#pragma unroll
            for (int i = 0; i < 4; ++i)
#pragma unroll
                for (int j = 0; j < 4; ++j)
                    acc[i][j] = __builtin_amdgcn_mfma_f32_16x16x32_bf16(af[i], bfv[j], acc[i][j], 0, 0, 0);
        }
        __syncthreads();
    }
#pragma unroll
    for (int i = 0; i < 4; ++i)
#pragma unroll
        for (int r = 0; r < 4; ++r) {
            int o = obase + i * 16 + lg * 4 + r;
            float bias = bo[o];
#pragma unroll
            for (int j = 0; j < 4; ++j) {
                int p = pbase + j * 16 + lr;
                size_t idx = ((size_t)n * C_ + o) * HW_ + p;
                out[idx] = acc[i][j][r] + bias + inp[idx];
            }
        }
}

extern "C" void kernel_launch(void* const* d_in, const int* in_sizes, int n_in,
                              void* d_out, int out_size, void* d_ws, size_t ws_size,
                              hipStream_t stream) {
    const float* input = (const float*)d_in[0];
    const float* cond  = (const float*)d_in[1];
    const float* Wqkv  = (const float*)d_in[2];
    const float* bqkv  = (const float*)d_in[3];
    const float* Wout  = (const float*)d_in[4];
    const float* bout  = (const float*)d_in[5];
    const float* Wmap  = (const float*)d_in[6];
    const float* bmap  = (const float*)d_in[7];
    float* out = (float*)d_out;

    char* wsb = (char*)d_ws;
    float* stats = (float*)(wsb + BO_STATS);
    float* affA  = (float*)(wsb + BO_AFFA);
    float* affB  = (float*)(wsb + BO_AFFB);
    u16* wqb = (u16*)(wsb + BO_WQ);
    u16* wob = (u16*)(wsb + BO_WO);
    u16* xt  = (u16*)(wsb + BO_XT);
    u16* Qb  = (u16*)(wsb + BO_Q);
    u16* Kb  = (u16*)(wsb + BO_K);
    u16* Vb  = (u16*)(wsb + BO_V);
    u16* Yb  = (u16*)(wsb + BO_Y);

    stats_kernel<<<dim3(B_ * GRP), 256, 0, stream>>>(input, stats);
    map_kernel<<<dim3(256), 256, 0, stream>>>(cond, Wmap, bmap, stats, affA, affB);
    wconv_kernel<<<dim3(1024), 256, 0, stream>>>(Wqkv, Wout, wqb, wob);
    xt_kernel<<<dim3(16, 8, 8), 256, 0, stream>>>(input, affA, affB, xt);
    qkv_mfma<<<dim3(768), 256, 0, stream>>>(wqb, bqkv, xt, Qb, Kb, Vb);
    attn_mfma<<<dim3(512), 256, 0, stream>>>(Qb, Kb, Vb, Yb);
    out_mfma<<<dim3(256), 256, 0, stream>>>(wob, bout, Yb, input, out);
}

// Round 6
// 184.208 us; speedup vs baseline: 3.6523x; 1.0223x over previous
//
#include <hip/hip_runtime.h>
#include <cstddef>
#include <cstdint>

typedef unsigned short u16;
typedef unsigned int   u32;
typedef short bf16x8 __attribute__((ext_vector_type(8)));
typedef float f32x4  __attribute__((ext_vector_type(4)));

#define B_    8
#define C_    512
#define HW_   1024
#define NHEAD 8
#define DH    64
#define GRP   32
#define CPG   16
#define O3    1536
#define COND  512
#define EPSV  1e-5f
#define LOG2E 1.4426950408889634f

// ---- workspace byte offsets ----
#define BO_STATS 0x0u        // 512 f32
#define BO_AFFA  0x1000u     // 4096 f32
#define BO_AFFB  0x5000u     // 4096 f32
#define BO_WQ    0x10000u    // 786432 bf16
#define BO_WO    0x190000u   // 262144 bf16
#define BO_XT    0x210000u   // [n][p][c] bf16, 8MB
#define BO_Q     0xA10000u   // [n][h][p][d] bf16 (pre-scaled by 0.125*log2e)
#define BO_K     0x1210000u  // [n][h][p][d] bf16
#define BO_V     0x1A10000u  // [n][h][d][p] bf16
#define BO_Y     0x2210000u  // [n][p][c] bf16

__device__ __forceinline__ u16 f2bf(float f) {
    u32 u = __float_as_uint(f);
    u += 0x7FFFu + ((u >> 16) & 1u);
    return (u16)(u >> 16);
}
__device__ __forceinline__ u32 cvtpk_bf16(float lo, float hi) {
    u32 r;
    asm("v_cvt_pk_bf16_f32 %0, %1, %2" : "=v"(r) : "v"(lo), "v"(hi));
    return r;
}
__device__ __forceinline__ bf16x8 as_frag(uint4 v) {
    union { uint4 u; bf16x8 f; } c; c.u = v; return c.f;
}

// ---------------- 1. GroupNorm statistics ----------------
__global__ __launch_bounds__(256) void stats_kernel(const float* __restrict__ x,
                                                    float* __restrict__ stats) {
    int bid = blockIdx.x;            // n*GRP + g
    int n = bid >> 5, g = bid & 31;
    const float4* base = (const float4*)(x + ((size_t)n * C_ + g * CPG) * HW_);
    float s1 = 0.f, s2 = 0.f;
    for (int i = threadIdx.x; i < CPG * HW_ / 4; i += 256) {
        float4 v = base[i];
        s1 += v.x + v.y + v.z + v.w;
        s2 += v.x*v.x + v.y*v.y + v.z*v.z + v.w*v.w;
    }
    __shared__ float r1[256], r2[256];
    r1[threadIdx.x] = s1; r2[threadIdx.x] = s2;
    __syncthreads();
    for (int s = 128; s > 0; s >>= 1) {
        if (threadIdx.x < s) {
            r1[threadIdx.x] += r1[threadIdx.x + s];
            r2[threadIdx.x] += r2[threadIdx.x + s];
        }
        __syncthreads();
    }
    if (threadIdx.x == 0) {
        const float inv = 1.f / (CPG * HW_);
        float mean = r1[0] * inv;
        float var  = r2[0] * inv - mean * mean;
        stats[bid * 2]     = mean;
        stats[bid * 2 + 1] = rsqrtf(var + EPSV);
    }
}

// ---------------- 2. cond map -> per-(n,c) affine (256 blocks, 8 thr/output) ----------------
__global__ __launch_bounds__(256) void map_kernel(const float* __restrict__ cond,
                                                  const float* __restrict__ Wmap,
                                                  const float* __restrict__ bmap,
                                                  const float* __restrict__ stats,
                                                  float* __restrict__ affA,
                                                  float* __restrict__ affB) {
    const int bid = blockIdx.x;              // 256: n = bid&7 (XCD-affine), chunk = bid>>3
    const int n = bid & 7, chunk = bid >> 3; // chunk == groupnorm group (16 ch each)
    const int c0 = chunk * 16;
    __shared__ float cs[COND];
    __shared__ float red[32];
    const int t = threadIdx.x;
    cs[t]       = cond[n * COND + t];
    cs[t + 256] = cond[n * COND + t + 256];
    __syncthreads();
    const int oi = t >> 3, part = t & 7;     // oi 0..31: [0,16)=scale ch, [16,32)=shift ch
    const int is_shift = oi >> 4, ci = oi & 15;
    const int row = is_shift * C_ + c0 + ci;
    const float* wrow = Wmap + (size_t)row * COND + part * 4;
    float acc = 0.f;
#pragma unroll
    for (int i = 0; i < 16; ++i) {
        float4 wv = *(const float4*)(wrow + i * 32);
        float4 c4 = *(const float4*)&cs[i * 32 + part * 4];
        acc = fmaf(wv.x, c4.x, acc);
        acc = fmaf(wv.y, c4.y, acc);
        acc = fmaf(wv.z, c4.z, acc);
        acc = fmaf(wv.w, c4.w, acc);
    }
    acc += __shfl_xor(acc, 1);
    acc += __shfl_xor(acc, 2);
    acc += __shfl_xor(acc, 4);
    if (part == 0) red[oi] = acc;
    __syncthreads();
    if (t < 16) {
        float scale = red[t]      + bmap[c0 + t];
        float shift = red[16 + t] + bmap[C_ + c0 + t];
        float mean = stats[(n * GRP + chunk) * 2];
        float rstd = stats[(n * GRP + chunk) * 2 + 1];
        float a = rstd * (scale + 1.f);
        float b = shift - mean * a;
        affA[n * C_ + c0 + t] = a;
        affB[n * C_ + c0 + t] = b;
    }
}

// ---------------- 3. weight fp32 -> bf16 ----------------
__global__ __launch_bounds__(256) void wconv_kernel(const float* __restrict__ wq,
                                                    const float* __restrict__ wo,
                                                    u16* __restrict__ wqb,
                                                    u16* __restrict__ wob) {
    int idx = blockIdx.x * 256 + threadIdx.x;     // quad index; grid = 1024 blocks
    if (idx < 196608) {                            // 786432/4
        float4 v = ((const float4*)wq)[idx];
        uint2 o;
        o.x = (u32)f2bf(v.x) | ((u32)f2bf(v.y) << 16);
        o.y = (u32)f2bf(v.z) | ((u32)f2bf(v.w) << 16);
        ((uint2*)wqb)[idx] = o;
    } else {
        int j = idx - 196608;                      // < 65536
        float4 v = ((const float4*)wo)[j];
        uint2 o;
        o.x = (u32)f2bf(v.x) | ((u32)f2bf(v.y) << 16);
        o.y = (u32)f2bf(v.z) | ((u32)f2bf(v.w) << 16);
        ((uint2*)wob)[j] = o;
    }
}

// ---------------- 4. x -> normed-x^T bf16  [n][p][c] ----------------
__global__ __launch_bounds__(256) void xt_kernel(const float* __restrict__ x,
                                                 const float* __restrict__ affA,
                                                 const float* __restrict__ affB,
                                                 u16* __restrict__ xt) {
    __shared__ float ts[64][65];
    const int t = threadIdx.x;
    const int n = blockIdx.z, c0 = blockIdx.y * 64, p0 = blockIdx.x * 64;
    {
        int cl = t >> 2, pq = t & 3;
        int c = c0 + cl;
        float a = affA[n * C_ + c], b = affB[n * C_ + c];
        const float* src = x + ((size_t)n * C_ + c) * HW_ + p0 + pq * 16;
#pragma unroll
        for (int ii = 0; ii < 4; ++ii) {
            float4 v = *(const float4*)(src + ii * 4);
            ts[cl][pq * 16 + ii * 4 + 0] = fmaf(v.x, a, b);
            ts[cl][pq * 16 + ii * 4 + 1] = fmaf(v.y, a, b);
            ts[cl][pq * 16 + ii * 4 + 2] = fmaf(v.z, a, b);
            ts[cl][pq * 16 + ii * 4 + 3] = fmaf(v.w, a, b);
        }
    }
    __syncthreads();
    {
        int pl = t >> 2, cq = t & 3;
        u16 us[16];
#pragma unroll
        for (int r = 0; r < 16; ++r) us[r] = f2bf(ts[cq * 16 + r][pl]);
        uint4 v0, v1;
        v0.x = (u32)us[0]  | ((u32)us[1]  << 16);
        v0.y = (u32)us[2]  | ((u32)us[3]  << 16);
        v0.z = (u32)us[4]  | ((u32)us[5]  << 16);
        v0.w = (u32)us[6]  | ((u32)us[7]  << 16);
        v1.x = (u32)us[8]  | ((u32)us[9]  << 16);
        v1.y = (u32)us[10] | ((u32)us[11] << 16);
        v1.z = (u32)us[12] | ((u32)us[13] << 16);
        v1.w = (u32)us[14] | ((u32)us[15] << 16);
        u16* dst = xt + ((size_t)n * HW_ + p0 + pl) * C_ + c0 + cq * 16;
        *(uint4*)dst = v0;
        *(uint4*)(dst + 8) = v1;
    }
}

// ---------------- 5. QKV GEMM (MFMA, LDS-staged via global_load_lds) ----------------
// A = wqb [o][c], B = xt [n*HW+p][c]; 128x128 tile, BK=64, swizzled chunks.
__global__ __launch_bounds__(256) void qkv_mfma(const u16* __restrict__ wqb,
                                                const float* __restrict__ bq,
                                                const u16* __restrict__ xt,
                                                u16* __restrict__ Qb,
                                                u16* __restrict__ Kb,
                                                u16* __restrict__ Vb) {
    __shared__ __attribute__((aligned(16))) char smem[40960];
    u16 (*As)[64] = (u16(*)[64])smem;                 // [128][64]
    u16 (*Bs)[64] = (u16(*)[64])(smem + 16384);       // [128][64]
    u16 (*tb)[64][80] = (u16(*)[64][80])smem;         // [4][64][80] (epilogue alias)

    const int t = threadIdx.x, lane = t & 63, w = t >> 6;
    const int wm = w >> 1, wn = w & 1;
    const int lr = lane & 15, lg = lane >> 4;
    const int b = blockIdx.x;                       // 768, XCD-affine decode
    const int n  = b & 7;
    const int px = (b >> 3) & 7;
    const int oy = b >> 6;                          // 0..11
    const int obase = oy * 128 + wm * 64;
    const int pbase = px * 128 + wn * 64;
    const int rsub = lane >> 3, csub = lane & 7;    // staging row / chunk
    const int schk = csub ^ rsub;                   // pre-swizzled source chunk

    f32x4 acc[4][4] = {};

    for (int k0 = 0; k0 < C_; k0 += 64) {
#pragma unroll
        for (int ii = 0; ii < 4; ++ii) {
            int rloc = w * 32 + ii * 8;             // 8 rows per call
            const u16* ga = wqb + (size_t)(oy * 128 + rloc + rsub) * C_ + k0 + schk * 8;
            __builtin_amdgcn_global_load_lds((const __attribute__((address_space(1))) void*)ga,
                                             (__attribute__((address_space(3))) void*)&As[rloc][0],
                                             16, 0, 0);
            const u16* gb = xt + (size_t)(n * HW_ + px * 128 + rloc + rsub) * C_ + k0 + schk * 8;
            __builtin_amdgcn_global_load_lds((const __attribute__((address_space(1))) void*)gb,
                                             (__attribute__((address_space(3))) void*)&Bs[rloc][0],
                                             16, 0, 0);
        }
        __syncthreads();                            // drains staging (vmcnt0) before reads
#pragma unroll
        for (int ks = 0; ks < 2; ++ks) {
            bf16x8 af[4], bfv[4];
#pragma unroll
            for (int f = 0; f < 4; ++f) {
                int ra = wm * 64 + f * 16 + lr;
                af[f] = as_frag(*(const uint4*)&As[ra][((ks * 4 + lg) ^ (ra & 7)) * 8]);
                int rb = wn * 64 + f * 16 + lr;
                bfv[f] = as_frag(*(const uint4*)&Bs[rb][((ks * 4 + lg) ^ (rb & 7)) * 8]);
            }
#pragma unroll
            for (int i = 0; i < 4; ++i)
#pragma unroll
                for (int j = 0; j < 4; ++j)
                    acc[i][j] = __builtin_amdgcn_mfma_f32_16x16x32_bf16(af[i], bfv[j], acc[i][j], 0, 0, 0);
        }
        __syncthreads();                            // reads done before next-tile staging
    }

    const int region = obase >> 9;            // 0=Q 1=K 2=V
    const int hsel = (obase & 511) >> 6;
    float bias[4][4];
#pragma unroll
    for (int i = 0; i < 4; ++i)
#pragma unroll
        for (int r = 0; r < 4; ++r) bias[i][r] = bq[obase + i * 16 + lg * 4 + r];

    if (region < 2) {
        const float sc = (region == 0) ? 0.125f * LOG2E : 1.0f;  // fold s^2*log2e into Q
        u16* dst = (region == 0) ? Qb : Kb;
#pragma unroll
        for (int i = 0; i < 4; ++i)
#pragma unroll
            for (int j = 0; j < 4; ++j) {
                uint2 v;
                v.x = (u32)f2bf((acc[i][j][0] + bias[i][0]) * sc) |
                      ((u32)f2bf((acc[i][j][1] + bias[i][1]) * sc) << 16);
                v.y = (u32)f2bf((acc[i][j][2] + bias[i][2]) * sc) |
                      ((u32)f2bf((acc[i][j][3] + bias[i][3]) * sc) << 16);
                *(uint2*)&tb[w][j * 16 + lr][i * 16 + lg * 4] = v;  // [p_local][o_local]
            }
        __syncthreads();
        const size_t gb = ((size_t)(n * NHEAD + hsel) * HW_ + pbase) * DH;
#pragma unroll
        for (int c = 0; c < 8; ++c) {
            uint4 v = *(const uint4*)&tb[w][lane][c * 8];
            *(uint4*)&dst[gb + (size_t)lane * DH + c * 8] = v;
        }
    } else {
#pragma unroll
        for (int i = 0; i < 4; ++i)
#pragma unroll
            for (int j = 0; j < 4; ++j) {
                int p = pbase + j * 16 + lr;
#pragma unroll
                for (int r = 0; r < 4; ++r) {
                    int d = i * 16 + lg * 4 + r;
                    Vb[((size_t)(n * NHEAD + hsel) * DH + d) * HW_ + p] =
                        f2bf(acc[i][j][r] + bias[i][r]);
                }
            }
    }
}

// ---------------- 6. flash attention (MFMA, 1024 blocks, 16 q-rows/wave) ----------------
__global__ __launch_bounds__(256) void attn_mfma(const u16* __restrict__ Qb,
                                                 const u16* __restrict__ Kb,
                                                 const u16* __restrict__ Vb,
                                                 u16* __restrict__ Yb) {
    __shared__ __attribute__((aligned(16))) u16 Kt[2][64][64]; // [buf][k][d], chunk^(k&7)
    __shared__ __attribute__((aligned(16))) u16 Vt[2][64][64]; // [buf][d][k], chunk^(d&7)
    __shared__ __attribute__((aligned(16))) u16 Pt[4][16][64]; // per-wave [q][k], chunk^(q&7)
    const int t = threadIdx.x, lane = t & 63, w = t >> 6;
    const int lr = lane & 15, lg = lane >> 4;
    const int b = blockIdx.x;                      // 1024; same (n,h) stays on one XCD
    const int nh = (b & 7) * 8 + ((b >> 3) & 7);
    const int q0g = (b >> 6) * 64;                 // 16 q-tiles of 64
    const size_t base = (size_t)nh * (HW_ * DH);
    const int srow = lane >> 3, schk = (lane & 7) ^ srow;   // staging source swizzle

    // Q fragments (pre-scaled by s^2*log2e), 16 q-rows per wave
    bf16x8 qf[2];
    {
        const uint4* Q4 = (const uint4*)(Qb + base);
        int qrow = q0g + w * 16 + lr;
        qf[0] = as_frag(Q4[qrow * 8 + lg]);
        qf[1] = as_frag(Q4[qrow * 8 + 4 + lg]);
    }

    auto stage = [&](int bb, int k0) {
#pragma unroll
        for (int ii = 0; ii < 2; ++ii) {
            int rk = w * 16 + ii * 8;
            const u16* gk = Kb + base + (size_t)(k0 + rk + srow) * DH + schk * 8;
            __builtin_amdgcn_global_load_lds((const __attribute__((address_space(1))) void*)gk,
                                             (__attribute__((address_space(3))) void*)&Kt[bb][rk][0],
                                             16, 0, 0);
            const u16* gv = Vb + base + (size_t)(rk + srow) * HW_ + k0 + schk * 8;
            __builtin_amdgcn_global_load_lds((const __attribute__((address_space(1))) void*)gv,
                                             (__attribute__((address_space(3))) void*)&Vt[bb][rk][0],
                                             16, 0, 0);
        }
    };

    float m_i = -3e38f, l_i = 0.f;
    f32x4 accy[4] = {};

    int buf = 0;
    stage(0, 0);
    for (int kt = 0; kt < 16; ++kt) {
        __syncthreads();                       // drains staging of buf + fences prev reads
        if (kt < 15) stage(buf ^ 1, (kt + 1) * 64);

        // S^T = K Q^T : lane holds q = w*16+lr, k = nf*16+lg*4+r
        f32x4 st[4] = {};
#pragma unroll
        for (int nf = 0; nf < 4; ++nf) {
#pragma unroll
            for (int ks = 0; ks < 2; ++ks) {
                int kl = nf * 16 + lr;
                bf16x8 kf = as_frag(*(const uint4*)&Kt[buf][kl][(((ks * 4 + lg) ^ (kl & 7)) * 8)]);
                st[nf] = __builtin_amdgcn_mfma_f32_16x16x32_bf16(kf, qf[ks], st[nf], 0, 0, 0);
            }
        }
        // lane-local softmax (exp2 domain) with defer-max (THR=8)
        {
            float x0 = fmaxf(fmaxf(st[0][0], st[0][1]), fmaxf(st[0][2], st[0][3]));
            float x1 = fmaxf(fmaxf(st[1][0], st[1][1]), fmaxf(st[1][2], st[1][3]));
            float x2 = fmaxf(fmaxf(st[2][0], st[2][1]), fmaxf(st[2][2], st[2][3]));
            float x3 = fmaxf(fmaxf(st[3][0], st[3][1]), fmaxf(st[3][2], st[3][3]));
            float rm = fmaxf(fmaxf(x0, x1), fmaxf(x2, x3));
            rm = fmaxf(rm, __shfl_xor(rm, 16));
            rm = fmaxf(rm, __shfl_xor(rm, 32));
            float nm = fmaxf(m_i, rm);
            if (!__all(nm - m_i <= 8.f)) {     // rescale only when max grew
                float fct = exp2f(m_i - nm);
                l_i *= fct;
#pragma unroll
                for (int df = 0; df < 4; ++df)
#pragma unroll
                    for (int r = 0; r < 4; ++r) accy[df][r] *= fct;
                m_i = nm;
            }
#pragma unroll
            for (int nf = 0; nf < 4; ++nf)
#pragma unroll
                for (int r = 0; r < 4; ++r) st[nf][r] = exp2f(st[nf][r] - m_i);
            float s0 = (st[0][0] + st[0][1]) + (st[0][2] + st[0][3]);
            float s1 = (st[1][0] + st[1][1]) + (st[1][2] + st[1][3]);
            float s2 = (st[2][0] + st[2][1]) + (st[2][2] + st[2][3]);
            float s3 = (st[3][0] + st[3][1]) + (st[3][2] + st[3][3]);
            float rs = (s0 + s1) + (s2 + s3);
            rs += __shfl_xor(rs, 16);
            rs += __shfl_xor(rs, 32);
            l_i += rs;
            // pack P -> per-wave LDS, swizzled; k = nf*16+lg*4..+3, q = lr
#pragma unroll
            for (int nf = 0; nf < 4; ++nf) {
                u32 lo = cvtpk_bf16(st[nf][0], st[nf][1]);
                u32 hi = cvtpk_bf16(st[nf][2], st[nf][3]);
                int c = nf * 2 + (lg >> 1);
                *(uint2*)&Pt[w][lr][((c ^ (lr & 7)) * 8) + (lg & 1) * 4] = make_uint2(lo, hi);
            }
        }
        // PV: Y^T[d][q] += V^T[d][k] P^T[k][q]
#pragma unroll
        for (int ks = 0; ks < 2; ++ks) {
            bf16x8 pf = as_frag(*(const uint4*)&Pt[w][lr][(((ks * 4 + lg) ^ (lr & 7)) * 8)]);
#pragma unroll
            for (int df = 0; df < 4; ++df) {
                int dl = df * 16 + lr;
                bf16x8 vf = as_frag(*(const uint4*)&Vt[buf][dl][(((ks * 4 + lg) ^ (dl & 7)) * 8)]);
                accy[df] = __builtin_amdgcn_mfma_f32_16x16x32_bf16(vf, pf, accy[df], 0, 0, 0);
            }
        }
        buf ^= 1;
    }

    // epilogue: normalize, direct global write (lane holds d = df*16+lg*4..+3, q = lr)
    const int n = nh >> 3, h = nh & 7;
    {
        float inv = 1.f / l_i;
        int p = q0g + w * 16 + lr;
#pragma unroll
        for (int df = 0; df < 4; ++df) {
            u32 lo = cvtpk_bf16(accy[df][0] * inv, accy[df][1] * inv);
            u32 hi = cvtpk_bf16(accy[df][2] * inv, accy[df][3] * inv);
            *(uint2*)&Yb[((size_t)(n * HW_ + p)) * C_ + h * DH + df * 16 + lg * 4] =
                make_uint2(lo, hi);
        }
    }
}

// ---------------- 7. out-proj GEMM (MFMA, LDS-staged) + bias + residual ----------------
__global__ __launch_bounds__(256) void out_mfma(const u16* __restrict__ wob,
                                                const float* __restrict__ bo,
                                                const u16* __restrict__ yb,
                                                const float* __restrict__ inp,
                                                float* __restrict__ out) {
    __shared__ __attribute__((aligned(16))) u16 As[128][64];
    __shared__ __attribute__((aligned(16))) u16 Bs[128][64];
    const int t = threadIdx.x, lane = t & 63, w = t >> 6;
    const int wm = w >> 1, wn = w & 1, lr = lane & 15, lg = lane >> 4;
    const int b = blockIdx.x;                    // 256, XCD-affine decode
    const int n  = b & 7;
    const int px = (b >> 3) & 7;
    const int oy = b >> 6;                       // 0..3
    const int obase = oy * 128 + wm * 64;
    const int pbase = px * 128 + wn * 64;
    const int rsub = lane >> 3, csub = lane & 7;
    const int schk = csub ^ rsub;

    f32x4 acc[4][4] = {};

    for (int k0 = 0; k0 < C_; k0 += 64) {
#pragma unroll
        for (int ii = 0; ii < 4; ++ii) {
            int rloc = w * 32 + ii * 8;
            const u16* ga = wob + (size_t)(oy * 128 + rloc + rsub) * C_ + k0 + schk * 8;
            __builtin_amdgcn_global_load_lds((const __attribute__((address_space(1))) void*)ga,
                                             (__attribute__((address_space(3))) void*)&As[rloc][0],
                                             16, 0, 0);
            const u16* gb = yb + (size_t)(n * HW_ + px * 128 + rloc + rsub) * C_ + k0 + schk * 8;
            __builtin_amdgcn_global_load_lds((const __attribute__((address_space(1))) void*)gb,
                                             (__attribute__((address_space(3))) void*)&Bs[rloc][0],
                                             16, 0, 0);
        }
        __syncthreads();
#pragma unroll
        for (int ks = 0; ks < 2; ++ks) {
            bf16x8 af[4], bfv[4];
#pragma unroll
            for (int f = 0; f < 4; ++f) {
                int ra = wm * 64 + f * 16 + lr;
                af[f] = as_frag(*(const uint4*)&As[ra][((ks * 4 + lg) ^ (ra & 7)) * 8]);
                int rb = wn * 64 + f * 16 + lr;
                bfv[f] = as_frag(*(const uint4*)&Bs[rb][((ks * 4 + lg) ^ (rb & 7)) * 8]);
            }
#pragma unroll
            for (int i = 0; i < 4; ++i)
#pragma unroll
                for (int j = 0; j < 4; ++j)
                    acc[i][j] = __builtin_amdgcn_mfma_f32_16x16x32_bf16(af[i], bfv[j], acc[i][j], 0, 0, 0);
        }
        __syncthreads();
    }
#pragma unroll
    for (int i = 0; i < 4; ++i)
#pragma unroll
        for (int r = 0; r < 4; ++r) {
            int o = obase + i * 16 + lg * 4 + r;
            float bias = bo[o];
#pragma unroll
            for (int j = 0; j < 4; ++j) {
                int p = pbase + j * 16 + lr;
                size_t idx = ((size_t)n * C_ + o) * HW_ + p;
                out[idx] = acc[i][j][r] + bias + inp[idx];
            }
        }
}

extern "C" void kernel_launch(void* const* d_in, const int* in_sizes, int n_in,
                              void* d_out, int out_size, void* d_ws, size_t ws_size,
                              hipStream_t stream) {
    const float* input = (const float*)d_in[0];
    const float* cond  = (const float*)d_in[1];
    const float* Wqkv  = (const float*)d_in[2];
    const float* bqkv  = (const float*)d_in[3];
    const float* Wout  = (const float*)d_in[4];
    const float* bout  = (const float*)d_in[5];
    const float* Wmap  = (const float*)d_in[6];
    const float* bmap  = (const float*)d_in[7];
    float* out = (float*)d_out;

    char* wsb = (char*)d_ws;
    float* stats = (float*)(wsb + BO_STATS);
    float* affA  = (float*)(wsb + BO_AFFA);
    float* affB  = (float*)(wsb + BO_AFFB);
    u16* wqb = (u16*)(wsb + BO_WQ);
    u16* wob = (u16*)(wsb + BO_WO);
    u16* xt  = (u16*)(wsb + BO_XT);
    u16* Qb  = (u16*)(wsb + BO_Q);
    u16* Kb  = (u16*)(wsb + BO_K);
    u16* Vb  = (u16*)(wsb + BO_V);
    u16* Yb  = (u16*)(wsb + BO_Y);

    stats_kernel<<<dim3(B_ * GRP), 256, 0, stream>>>(input, stats);
    map_kernel<<<dim3(256), 256, 0, stream>>>(cond, Wmap, bmap, stats, affA, affB);
    wconv_kernel<<<dim3(1024), 256, 0, stream>>>(Wqkv, Wout, wqb, wob);
    xt_kernel<<<dim3(16, 8, 8), 256, 0, stream>>>(input, affA, affB, xt);
    qkv_mfma<<<dim3(768), 256, 0, stream>>>(wqb, bqkv, xt, Qb, Kb, Vb);
    attn_mfma<<<dim3(1024), 256, 0, stream>>>(Qb, Kb, Vb, Yb);
    out_mfma<<<dim3(256), 256, 0, stream>>>(wob, bout, Yb, input, out);
}